// Round 1
// baseline (3262.827 us; speedup 1.0000x reference)
//
#include <hip/hip_runtime.h>
#include <math.h>

#define BATCH 8
#define NPTS 8192
#define CFEAT 64
#define NC 2048           // S centers
#define KNN 32
#define NSCOL (NC*KNN)    // 65536 columns per batch
#define R2 0.0625f        // radius^2
#define GN_EPS 1e-5f
#define SBINS 32          // stat partial bins (cuts atomic contention 32x)

// ---- workspace layout (bytes) ----
#define OFF_CIDX   0ull
#define OFF_NIDX   65536ull
#define OFF_CENT   2162688ull
#define OFF_STATSP 2359296ull            // 3 layers x 32 bins x 128 fl = 49152 B
#define OFF_STATSF 2408448ull            // 3 x 128 fl = 1536 B
#define OFF_WT     2410496ull            // 16576 fl = 66304 B
#define OFF_XALL   4194304ull            // 17,825,792 B
#define OFF_Y      23068672ull           // 134,217,728 B
#define WS_NEEDED  (OFF_Y + 8ull*64*NSCOL*4ull)   // 150 MiB

static __device__ __forceinline__ unsigned f2bf(float f) {
    unsigned u = __float_as_uint(f);
    return (u + 0x7fffu + ((u >> 16) & 1u)) >> 16;   // RNE, finite inputs
}

// ---- DPP wave-64 max reduce (VALU-latency, replaces DS-pipe shuffles) ----
// row_shr:1/2/4/8 then row_bcast:15/31; result valid in lane 63.
// bound_ctrl=false + old=x: lanes with invalid src keep x; max(x,x)=x.
template<int CTRL>
static __device__ __forceinline__ float dppmaxf(float x) {
    int y = __builtin_amdgcn_update_dpp(__float_as_int(x), __float_as_int(x),
                                        CTRL, 0xf, 0xf, false);
    return fmaxf(x, __int_as_float(y));
}
template<int CTRL>
static __device__ __forceinline__ unsigned dppmaxu(unsigned x) {
    unsigned y = (unsigned)__builtin_amdgcn_update_dpp((int)x, (int)x,
                                                       CTRL, 0xf, 0xf, false);
    return x > y ? x : y;
}
static __device__ __forceinline__ float wave_max_f(float x) {
    x = dppmaxf<0x111>(x);   // row_shr:1
    x = dppmaxf<0x112>(x);   // row_shr:2
    x = dppmaxf<0x114>(x);   // row_shr:4
    x = dppmaxf<0x118>(x);   // row_shr:8
    x = dppmaxf<0x142>(x);   // row_bcast:15
    x = dppmaxf<0x143>(x);   // row_bcast:31
    return __int_as_float(__builtin_amdgcn_readlane(__float_as_int(x), 63));
}
static __device__ __forceinline__ unsigned wave_max_u(unsigned x) {
    x = dppmaxu<0x111>(x);
    x = dppmaxu<0x112>(x);
    x = dppmaxu<0x114>(x);
    x = dppmaxu<0x118>(x);
    x = dppmaxu<0x142>(x);
    x = dppmaxu<0x143>(x);
    return (unsigned)__builtin_amdgcn_readlane((int)x, 63);
}

// =====================================================================
// prep: zero stat partials/finals; transpose weights to [i][o] layout.
// =====================================================================
__global__ void prep_kernel(const float* __restrict__ w0, const float* __restrict__ w1,
                            const float* __restrict__ w2, float* __restrict__ statsP,
                            float* __restrict__ statsF, float* __restrict__ wt)
{
    const int t = blockIdx.x * 256 + threadIdx.x;
    if (t < 3 * SBINS * 128) statsP[t] = 0.f;
    if (t < 384) statsF[t] = 0.f;
    if (t < 64 * 67) { int o = t / 67, i = t - o * 67; wt[i * 64 + o] = w0[t]; }
    if (t < 64 * 64) { int o = t >> 6, i = t & 63;     wt[4288 + i * 64 + o] = w1[t]; }
    if (t < 128 * 64){ int o = t >> 6, i = t & 63;     wt[8384 + i * 128 + o] = w2[t]; }
}

// =====================================================================
__global__ void reduce_stats(const float* __restrict__ statsPL, float* __restrict__ statsFL)
{
    const int t = threadIdx.x;
    if (t < 128) {
        float s = 0.f;
#pragma unroll
        for (int bin = 0; bin < SBINS; ++bin) s += statsPL[bin * 128 + t];
        statsFL[t] = s;
    }
}

// =====================================================================
// build point-major input records: xall[b][p][0..2]=coords, [3..66]=feats,
// [67]=pad (272 B record, float4-aligned)
// =====================================================================
__global__ __launch_bounds__(256) void build_xall(const float* __restrict__ coords,
                                                  const float* __restrict__ feats,
                                                  float* __restrict__ xall)
{
    const int tid = blockIdx.x * 256 + threadIdx.x;   // b*NPTS + p
    const int b = tid >> 13, p = tid & (NPTS - 1);
    const float* cb = coords + (size_t)b * 3 * NPTS;
    const float* fb = feats + (size_t)b * CFEAT * NPTS;
    float* xp = xall + (size_t)tid * 68;
    xp[0] = cb[p]; xp[1] = cb[NPTS + p]; xp[2] = cb[2 * NPTS + p];
#pragma unroll
    for (int c = 0; c < CFEAT; ++c) xp[3 + c] = fb[c * NPTS + p];
    xp[67] = 0.f;
}

// =====================================================================
// FPS v4: 1 block/batch, 256 threads, 32 pts/thread pinned in VGPRs.
// Reduce rewritten from 6-step u64 ds_swizzle chain (~700-800 cy of
// serial DS latency) to a two-phase DPP VALU reduce (~100 cy):
//   phase 1: wave max of mind (f32, row_shr/row_bcast + readlane 63)
//   phase 2: wave max of (NPTS-1-bi) among lanes tied at max
// Tie-break identical to the packed-u64 scheme (lowest global index;
// bi unique mod 256 so the winner lane is unique, keys globally
// distinct so the cross-wave combine is deterministic).
// Winner lane also carries the next center's coords through the LDS
// slot, removing the post-barrier sx/sy/sz[cur] broadcast reads from
// the serial chain. One barrier/iter, double-buffered slots.
// No-contract fp32 matches numpy ((dx*dx+dy*dy)+dz*dz) bitwise.
// =====================================================================
struct FpsSlots {
    unsigned long long key[4];
    float x[4], y[4], z[4];
};

__global__ __launch_bounds__(256) void fps_kernel(const float* __restrict__ coords,
                                                  int* __restrict__ cidx)
{
    extern __shared__ float smem[];
    float* sx = smem;
    float* sy = smem + NPTS;
    float* sz = smem + 2 * NPTS;
    FpsSlots* slots = (FpsSlots*)(smem + 3 * NPTS);   // [2], 98304B offset (8-aligned)

    const int b = blockIdx.x;
    const int t = threadIdx.x;
    const int wid = t >> 6;
    const float* cb = coords + (size_t)b * 3 * NPTS;

    float X[32], Y[32], Z[32], mind[32];
#pragma unroll
    for (int j = 0; j < 32; ++j) {
        int p = t + j * 256;
        X[j] = cb[p];
        Y[j] = cb[NPTS + p];
        Z[j] = cb[2 * NPTS + p];
        sx[p] = X[j]; sy[p] = Y[j]; sz[p] = Z[j];
        mind[j] = 1e10f;
        // pin private copies in VGPRs: compiler may no longer fold them
        // into ds_reads of sx/sy/sz
        asm volatile("" : "+v"(X[j]), "+v"(Y[j]), "+v"(Z[j]));
    }
    if (t == 0) cidx[b * NC] = 0;
    __syncthreads();

    float lx = sx[0], ly = sy[0], lz = sz[0];   // first center = point 0

    for (int it = 1; it < NC; ++it) {
        float bv = -1.0f; int bi = 0;
#pragma unroll
        for (int j = 0; j < 32; ++j) {
            float dx = __fsub_rn(X[j], lx);
            float dy = __fsub_rn(Y[j], ly);
            float dz = __fsub_rn(Z[j], lz);
            float d  = __fadd_rn(__fadd_rn(__fmul_rn(dx, dx), __fmul_rn(dy, dy)),
                                 __fmul_rn(dz, dz));
            float nm = fminf(mind[j], d);
            mind[j] = nm;
            if (nm > bv) { bv = nm; bi = t + j * 256; }   // strict >: lowest idx
        }
        // ---- wave reduce: value first, then lowest index among ties ----
        const float wm = wave_max_f(bv);
        const unsigned myrb = (unsigned)(NPTS - 1 - bi);
        const unsigned rb = (bv == wm) ? myrb : 0u;
        const unsigned wc = wave_max_u(rb);

        FpsSlots* sl = slots + (it & 1);                  // double buffer
        if (bv == wm && myrb == wc) {                     // unique winner lane
            sl->key[wid] = ((unsigned long long)__float_as_uint(wm) << 32)
                         | (unsigned long long)wc;
            sl->x[wid] = sx[bi];
            sl->y[wid] = sy[bi];
            sl->z[wid] = sz[bi];
        }
        __syncthreads();
        unsigned long long k0 = sl->key[0], k1 = sl->key[1];
        unsigned long long k2 = sl->key[2], k3 = sl->key[3];
        float nx = sl->x[0], ny = sl->y[0], nz = sl->z[0];
        unsigned long long bk = k0;
        if (k1 > bk) { bk = k1; nx = sl->x[1]; ny = sl->y[1]; nz = sl->z[1]; }
        if (k2 > bk) { bk = k2; nx = sl->x[2]; ny = sl->y[2]; nz = sl->z[2]; }
        if (k3 > bk) { bk = k3; nx = sl->x[3]; ny = sl->y[3]; nz = sl->z[3]; }
        lx = nx; ly = ny; lz = nz;
        if (t == 0) cidx[b * NC + it] = NPTS - 1 - (int)(bk & 0xffffffffu);
    }
}

// =====================================================================
// Ball query -> nidx + centers. EXPANDED d2 form (cn+pn)-2*cp, no fma.
// =====================================================================
__global__ __launch_bounds__(256) void bq_kernel(const float* __restrict__ coords,
                                                 const int* __restrict__ cidx,
                                                 int* __restrict__ nidx,
                                                 float* __restrict__ centers)
{
    const int s = blockIdx.x, b = blockIdx.y, t = threadIdx.x;
    __shared__ int s_idx[KNN];
    __shared__ int s_pref[9];
    __shared__ float s_c[3];
    __shared__ float s_cn;
    const float* cb = coords + (size_t)b * 3 * NPTS;
    if (t == 0) {
        int ci = cidx[b * NC + s];
        float cx = cb[ci], cy = cb[NPTS + ci], cz = cb[2 * NPTS + ci];
        s_c[0] = cx; s_c[1] = cy; s_c[2] = cz;
        s_cn = __fadd_rn(__fadd_rn(__fmul_rn(cx, cx), __fmul_rn(cy, cy)),
                         __fmul_rn(cz, cz));
    }
    __syncthreads();
    const float cx = s_c[0], cy = s_c[1], cz = s_c[2], cn = s_cn;
    const int base = t * 32;
    int cnt = 0;
    for (int j = 0; j < 32; ++j) {
        int p = base + j;
        float x = cb[p], y = cb[NPTS + p], z = cb[2 * NPTS + p];
        float pn = __fadd_rn(__fadd_rn(__fmul_rn(x, x), __fmul_rn(y, y)), __fmul_rn(z, z));
        float cp = __fadd_rn(__fadd_rn(__fmul_rn(cx, x), __fmul_rn(cy, y)), __fmul_rn(cz, z));
        float d2 = __fsub_rn(__fadd_rn(cn, pn), __fmul_rn(2.0f, cp));
        if (d2 < R2) ++cnt;
    }
    const int lane = t & 63, wid = t >> 6;
    int incl = cnt;
    for (int o = 1; o < 64; o <<= 1) {
        int v = __shfl_up(incl, o);
        if (lane >= o) incl += v;
    }
    if (lane == 63) s_pref[wid] = incl;
    __syncthreads();
    int ex = incl - cnt;
    for (int w = 0; w < wid; ++w) ex += s_pref[w];
    if (t == 255) s_pref[8] = ex + cnt;
    if (ex < KNN && cnt > 0) {
        int slot = ex;
        for (int j = 0; j < 32 && slot < KNN; ++j) {
            int p = base + j;
            float x = cb[p], y = cb[NPTS + p], z = cb[2 * NPTS + p];
            float pn = __fadd_rn(__fadd_rn(__fmul_rn(x, x), __fmul_rn(y, y)), __fmul_rn(z, z));
            float cp = __fadd_rn(__fadd_rn(__fmul_rn(cx, x), __fmul_rn(cy, y)), __fmul_rn(cz, z));
            float d2 = __fsub_rn(__fadd_rn(cn, pn), __fmul_rn(2.0f, cp));
            if (d2 < R2) { s_idx[slot] = p; ++slot; }
        }
    }
    __syncthreads();
    const int total = s_pref[8];
    if (t < KNN) {
        int v = (total == 0) ? 0 : ((t < total) ? s_idx[t] : s_idx[0]);
        nidx[(b * NC + s) * KNN + t] = v;
    }
    if (t < 3) centers[(b * NC + s) * 3 + t] = s_c[t];
}

// =====================================================================
// Layer 1: block = 64 cols x 4 out-chunks of 16. Gather staged in LDS
// xs[68][64] fp32; per-thread state is only acc[16] (no spill).
// =====================================================================
__global__ __launch_bounds__(256) void l1_kernel(const float* __restrict__ xall,
                                                 const int* __restrict__ nidx,
                                                 const float* __restrict__ centers,
                                                 const float* __restrict__ wt,
                                                 const float* __restrict__ b0,
                                                 float* __restrict__ Y,
                                                 float* __restrict__ statsPL)
{
    __shared__ float sw[67 * 64 + 64];
    __shared__ float xs[68 * 64];
    __shared__ float s_sum[8], s_sq[8];
    const int b = blockIdx.y, t = threadIdx.x;
    const int col = t & 63, q = t >> 6;
    const int n = blockIdx.x * 64 + col;
    for (int i = t; i < 67 * 64; i += 256) sw[i] = wt[i];
    if (t < 64) sw[67 * 64 + t] = b0[t];
    if (t < 8) { s_sum[t] = 0.f; s_sq[t] = 0.f; }
    const int s = n >> 5, k = n & 31;
    const int p = nidx[(b * NC + s) * KNN + k];
    const float4* xp4 = (const float4*)(xall + (size_t)(b * NPTS + p) * 68);
    const float* cc = centers + (size_t)(b * NC + s) * 3;
#pragma unroll
    for (int r = 0; r < 4; ++r) {
        float4 v = xp4[q * 4 + r];
        int ch = (q * 4 + r) * 4;
        if (ch == 0) { v.x -= cc[0]; v.y -= cc[1]; v.z -= cc[2]; }
        xs[(ch + 0) * 64 + col] = v.x;
        xs[(ch + 1) * 64 + col] = v.y;
        xs[(ch + 2) * 64 + col] = v.z;
        xs[(ch + 3) * 64 + col] = v.w;
    }
    if (q == 3) {
        float4 v = xp4[16];
        xs[64 * 64 + col] = v.x;
        xs[65 * 64 + col] = v.y;
        xs[66 * 64 + col] = v.z;
        xs[67 * 64 + col] = v.w;
    }
    __syncthreads();
    float acc[16];
#pragma unroll
    for (int o = 0; o < 16; ++o) acc[o] = sw[67 * 64 + q * 16 + o];
    for (int i = 0; i < 67; ++i) {
        float xv = xs[i * 64 + col];
        const float* wr = sw + i * 64 + q * 16;
#pragma unroll
        for (int o = 0; o < 16; ++o) acc[o] = fmaf(wr[o], xv, acc[o]);
    }
    float* yb = Y + (size_t)b * 64 * NSCOL + n;
#pragma unroll
    for (int o = 0; o < 16; ++o) yb[(size_t)(q * 16 + o) * NSCOL] = acc[o];
#pragma unroll
    for (int g = 0; g < 2; ++g) {
        float sv = 0.f, sq = 0.f;
#pragma unroll
        for (int j = 0; j < 8; ++j) { float vv = acc[g * 8 + j]; sv += vv; sq = fmaf(vv, vv, sq); }
#pragma unroll
        for (int o = 32; o > 0; o >>= 1) { sv += __shfl_xor(sv, o); sq += __shfl_xor(sq, o); }
        if ((t & 63) == 0) { atomicAdd(&s_sum[q * 2 + g], sv); atomicAdd(&s_sq[q * 2 + g], sq); }
    }
    __syncthreads();
    if (t < 16) {
        const int bin = blockIdx.x & (SBINS - 1);
        const int g = t >> 1, kk = t & 1;
        atomicAdd(&statsPL[bin * 128 + (b * 8 + g) * 2 + kk], kk ? s_sq[g] : s_sum[g]);
    }
}

// =====================================================================
// Layer 2: in-place, block = 64 cols x 4 out-chunks of 16.
// =====================================================================
__global__ __launch_bounds__(256) void l2_kernel(const float* __restrict__ wt1,
                                                 const float* __restrict__ b1,
                                                 const float* __restrict__ g0,
                                                 const float* __restrict__ be0,
                                                 const float* __restrict__ statsF_in,
                                                 float* __restrict__ statsPL,
                                                 float* __restrict__ Y)
{
    __shared__ float sw[64 * 64 + 64];
    __shared__ float xs[64 * 64];
    __shared__ float sA[64], sB[64];
    __shared__ float s_sum[8], s_sq[8];
    const int b = blockIdx.y, t = threadIdx.x;
    const int col = t & 63, q = t >> 6;
    const int n = blockIdx.x * 64 + col;
    for (int i = t; i < 64 * 64; i += 256) sw[i] = wt1[i];
    if (t < 64) {
        sw[64 * 64 + t] = b1[t];
        const int g = t >> 3;
        const float inv = 1.0f / (8.0f * NSCOL);
        float mu = statsF_in[(b * 8 + g) * 2 + 0] * inv;
        float var = statsF_in[(b * 8 + g) * 2 + 1] * inv - mu * mu;
        float A = (1.0f / sqrtf(var + GN_EPS)) * g0[t];
        sA[t] = A; sB[t] = be0[t] - mu * A;
    }
    if (t < 8) { s_sum[t] = 0.f; s_sq[t] = 0.f; }
    __syncthreads();
    float* yb = Y + (size_t)b * 64 * NSCOL + n;
#pragma unroll
    for (int r = 0; r < 16; ++r) {
        int i = q * 16 + r;
        float raw = yb[(size_t)i * NSCOL];
        float v = fmaf(raw, sA[i], sB[i]);
        xs[i * 64 + col] = v * __builtin_amdgcn_rcpf(1.0f + __expf(-v));
    }
    __syncthreads();
    float acc[16];
#pragma unroll
    for (int o = 0; o < 16; ++o) acc[o] = sw[64 * 64 + q * 16 + o];
    for (int i = 0; i < 64; ++i) {
        float xv = xs[i * 64 + col];
        const float* wr = sw + i * 64 + q * 16;
#pragma unroll
        for (int o = 0; o < 16; ++o) acc[o] = fmaf(wr[o], xv, acc[o]);
    }
#pragma unroll
    for (int o = 0; o < 16; ++o) yb[(size_t)(q * 16 + o) * NSCOL] = acc[o];
#pragma unroll
    for (int g = 0; g < 2; ++g) {
        float sv = 0.f, sq = 0.f;
#pragma unroll
        for (int j = 0; j < 8; ++j) { float vv = acc[g * 8 + j]; sv += vv; sq = fmaf(vv, vv, sq); }
#pragma unroll
        for (int o = 32; o > 0; o >>= 1) { sv += __shfl_xor(sv, o); sq += __shfl_xor(sq, o); }
        if ((t & 63) == 0) { atomicAdd(&s_sum[q * 2 + g], sv); atomicAdd(&s_sq[q * 2 + g], sq); }
    }
    __syncthreads();
    if (t < 16) {
        const int bin = blockIdx.x & (SBINS - 1);
        const int g = t >> 1, kk = t & 1;
        atomicAdd(&statsPL[bin * 128 + (b * 8 + g) * 2 + kk], kk ? s_sq[g] : s_sum[g]);
    }
}

// =====================================================================
// Layer 3: in-place, block = 64 cols x 4 out-chunks of 32 (128 out).
// Output bf16 pair-packed into the same 256B/col footprint.
// =====================================================================
__global__ __launch_bounds__(256) void l3_kernel(const float* __restrict__ wt2,
                                                 const float* __restrict__ b2,
                                                 const float* __restrict__ g1,
                                                 const float* __restrict__ be1,
                                                 const float* __restrict__ statsF_in,
                                                 float* __restrict__ statsPL,
                                                 float* __restrict__ Y)
{
    __shared__ float sw[64 * 128 + 128];
    __shared__ float xs[64 * 64];
    __shared__ float sA[64], sB[64];
    __shared__ float s_sum[8], s_sq[8];
    const int b = blockIdx.y, t = threadIdx.x;
    const int col = t & 63, q = t >> 6;
    const int n = blockIdx.x * 64 + col;
    for (int i = t; i < 64 * 128; i += 256) sw[i] = wt2[i];
    if (t < 128) sw[64 * 128 + t] = b2[t];
    if (t < 64) {
        const int g = t >> 3;
        const float inv = 1.0f / (8.0f * NSCOL);
        float mu = statsF_in[(b * 8 + g) * 2 + 0] * inv;
        float var = statsF_in[(b * 8 + g) * 2 + 1] * inv - mu * mu;
        float A = (1.0f / sqrtf(var + GN_EPS)) * g1[t];
        sA[t] = A; sB[t] = be1[t] - mu * A;
    }
    if (t < 8) { s_sum[t] = 0.f; s_sq[t] = 0.f; }
    __syncthreads();
    float* yb = Y + (size_t)b * 64 * NSCOL + n;
#pragma unroll
    for (int r = 0; r < 16; ++r) {
        int i = q * 16 + r;
        float raw = yb[(size_t)i * NSCOL];
        float v = fmaf(raw, sA[i], sB[i]);
        xs[i * 64 + col] = v * __builtin_amdgcn_rcpf(1.0f + __expf(-v));
    }
    __syncthreads();
    float acc[32];
#pragma unroll
    for (int o = 0; o < 32; ++o) acc[o] = sw[64 * 128 + q * 32 + o];
    for (int i = 0; i < 64; ++i) {
        float xv = xs[i * 64 + col];
        const float* wr = sw + i * 128 + q * 32;
#pragma unroll
        for (int o = 0; o < 32; ++o) acc[o] = fmaf(wr[o], xv, acc[o]);
    }
#pragma unroll
    for (int g = 0; g < 2; ++g) {
        float sv = 0.f, sq = 0.f;
#pragma unroll
        for (int j = 0; j < 16; ++j) { float vv = acc[g * 16 + j]; sv += vv; sq = fmaf(vv, vv, sq); }
#pragma unroll
        for (int o = 32; o > 0; o >>= 1) { sv += __shfl_xor(sv, o); sq += __shfl_xor(sq, o); }
        if ((t & 63) == 0) { atomicAdd(&s_sum[q * 2 + g], sv); atomicAdd(&s_sq[q * 2 + g], sq); }
    }
    unsigned* yu = (unsigned*)yb;
#pragma unroll
    for (int j = 0; j < 16; ++j) {
        unsigned u = f2bf(acc[2 * j]) | (f2bf(acc[2 * j + 1]) << 16);
        yu[(size_t)(q * 16 + j) * NSCOL] = u;
    }
    __syncthreads();
    if (t < 16) {
        const int bin = blockIdx.x & (SBINS - 1);
        const int g = t >> 1, kk = t & 1;
        atomicAdd(&statsPL[bin * 128 + (b * 8 + g) * 2 + kk], kk ? s_sq[g] : s_sum[g]);
    }
}

// =====================================================================
// Finalize: GN3 + SiLU + max over K. Thread per (b, channel-PAIR, s).
// =====================================================================
__global__ __launch_bounds__(256) void fin_kernel(const unsigned* __restrict__ Yu,
                                                  const float* __restrict__ g2,
                                                  const float* __restrict__ be2,
                                                  const float* __restrict__ stats,
                                                  float* __restrict__ out)
{
    const int tid = blockIdx.x * 256 + threadIdx.x;
    const int s = tid & (NC - 1);
    const int cp = (tid >> 11) & 63;
    const int b = tid >> 17;
    const int g = cp >> 3;
    const float inv = 1.0f / (16.0f * NSCOL);
    float mu = stats[(b * 8 + g) * 2 + 0] * inv;
    float var = stats[(b * 8 + g) * 2 + 1] * inv - mu * mu;
    float rs = 1.0f / sqrtf(var + GN_EPS);
    const int c0 = cp * 2, c1 = c0 + 1;
    float A0 = rs * g2[c0], B0 = be2[c0] - mu * A0;
    float A1 = rs * g2[c1], B1 = be2[c1] - mu * A1;
    const unsigned* yb = Yu + (size_t)(b * 64 + cp) * NSCOL + s * KNN;
    float m0 = -INFINITY, m1 = -INFINITY;
#pragma unroll
    for (int qq = 0; qq < 8; ++qq) {
        uint4 v = ((const uint4*)yb)[qq];
        unsigned uu[4] = {v.x, v.y, v.z, v.w};
#pragma unroll
        for (int r = 0; r < 4; ++r) {
            float f0 = __uint_as_float(uu[r] << 16);
            float f1 = __uint_as_float(uu[r] & 0xffff0000u);
            float v0 = fmaf(f0, A0, B0);
            v0 = v0 * __builtin_amdgcn_rcpf(1.0f + __expf(-v0));
            m0 = fmaxf(m0, v0);
            float v1 = fmaf(f1, A1, B1);
            v1 = v1 * __builtin_amdgcn_rcpf(1.0f + __expf(-v1));
            m1 = fmaxf(m1, v1);
        }
    }
    out[(size_t)(b * 128 + c0) * NC + s] = m0;
    out[(size_t)(b * 128 + c1) * NC + s] = m1;
}

// =====================================================================
extern "C" void kernel_launch(void* const* d_in, const int* in_sizes, int n_in,
                              void* d_out, int out_size, void* d_ws, size_t ws_size,
                              hipStream_t stream)
{
    if (ws_size < WS_NEEDED) return;

    const float* coords = (const float*)d_in[0];
    const float* feats  = (const float*)d_in[1];
    const float* w0  = (const float*)d_in[2];
    const float* b0  = (const float*)d_in[3];
    const float* g0  = (const float*)d_in[4];
    const float* be0 = (const float*)d_in[5];
    const float* w1  = (const float*)d_in[6];
    const float* b1  = (const float*)d_in[7];
    const float* g1  = (const float*)d_in[8];
    const float* be1 = (const float*)d_in[9];
    const float* w2  = (const float*)d_in[10];
    const float* b2  = (const float*)d_in[11];
    const float* g2  = (const float*)d_in[12];
    const float* be2 = (const float*)d_in[13];
    float* out = (float*)d_out;

    char* ws = (char*)d_ws;
    int*   cidx    = (int*)(ws + OFF_CIDX);
    int*   nidx    = (int*)(ws + OFF_NIDX);
    float* centers = (float*)(ws + OFF_CENT);
    float* statsP  = (float*)(ws + OFF_STATSP);   // [3][SBINS][128]
    float* statsF  = (float*)(ws + OFF_STATSF);   // [3][128]
    float* wt      = (float*)(ws + OFF_WT);
    float* xall    = (float*)(ws + OFF_XALL);
    float* Ybuf    = (float*)(ws + OFF_Y);

    prep_kernel<<<48, 256, 0, stream>>>(w0, w1, w2, statsP, statsF, wt);
    build_xall<<<(BATCH * NPTS) / 256, 256, 0, stream>>>(coords, feats, xall);
    // dynamic LDS: 3*NPTS floats (coords) + 2 double-buffered winner slots
    fps_kernel<<<BATCH, 256, 3 * NPTS * 4 + 256, stream>>>(coords, cidx);
    bq_kernel<<<dim3(NC, BATCH), 256, 0, stream>>>(coords, cidx, nidx, centers);

    const dim3 lgrid(NSCOL / 64, BATCH);
    l1_kernel<<<lgrid, 256, 0, stream>>>(xall, nidx, centers, wt, b0, Ybuf, statsP);
    reduce_stats<<<1, 128, 0, stream>>>(statsP, statsF);
    l2_kernel<<<lgrid, 256, 0, stream>>>(wt + 4288, b1, g0, be0,
                                         statsF, statsP + SBINS * 128, Ybuf);
    reduce_stats<<<1, 128, 0, stream>>>(statsP + SBINS * 128, statsF + 128);
    l3_kernel<<<lgrid, 256, 0, stream>>>(wt + 8384, b2, g1, be1,
                                         statsF + 128, statsP + 2 * SBINS * 128, Ybuf);
    reduce_stats<<<1, 128, 0, stream>>>(statsP + 2 * SBINS * 128, statsF + 256);
    fin_kernel<<<(BATCH * 64 * NC) / 256, 256, 0, stream>>>(
        (const unsigned*)Ybuf, g2, be2, statsF + 256, out);
    (void)in_sizes; (void)n_in; (void)out_size;
}

// Round 2
// 2973.674 us; speedup vs baseline: 1.0972x; 1.0972x over previous
//
#include <hip/hip_runtime.h>
#include <math.h>

#define BATCH 8
#define NPTS 8192
#define CFEAT 64
#define NC 2048           // S centers
#define KNN 32
#define NSCOL (NC*KNN)    // 65536 columns per batch
#define R2 0.0625f        // radius^2
#define GN_EPS 1e-5f
#define SBINS 32          // stat partial bins (cuts atomic contention 32x)

// ---- workspace layout (bytes) ----
#define OFF_CIDX   0ull
#define OFF_NIDX   65536ull
#define OFF_CENT   2162688ull
#define OFF_STATSP 2359296ull            // 3 layers x 32 bins x 128 fl = 49152 B
#define OFF_STATSF 2408448ull            // 3 x 128 fl = 1536 B
#define OFF_WT     2410496ull            // 16576 fl = 66304 B
#define OFF_XALL   4194304ull            // 17,825,792 B
#define OFF_Y      23068672ull           // 134,217,728 B
#define WS_NEEDED  (OFF_Y + 8ull*64*NSCOL*4ull)   // 150 MiB

typedef float v2f __attribute__((ext_vector_type(2)));

static __device__ __forceinline__ unsigned f2bf(float f) {
    unsigned u = __float_as_uint(f);
    return (u + 0x7fffu + ((u >> 16) & 1u)) >> 16;   // RNE, finite inputs
}

// =====================================================================
// prep: zero stat partials/finals; transpose weights to [i][o] layout.
// =====================================================================
__global__ void prep_kernel(const float* __restrict__ w0, const float* __restrict__ w1,
                            const float* __restrict__ w2, float* __restrict__ statsP,
                            float* __restrict__ statsF, float* __restrict__ wt)
{
    const int t = blockIdx.x * 256 + threadIdx.x;
    if (t < 3 * SBINS * 128) statsP[t] = 0.f;
    if (t < 384) statsF[t] = 0.f;
    if (t < 64 * 67) { int o = t / 67, i = t - o * 67; wt[i * 64 + o] = w0[t]; }
    if (t < 64 * 64) { int o = t >> 6, i = t & 63;     wt[4288 + i * 64 + o] = w1[t]; }
    if (t < 128 * 64){ int o = t >> 6, i = t & 63;     wt[8384 + i * 128 + o] = w2[t]; }
}

// =====================================================================
__global__ void reduce_stats(const float* __restrict__ statsPL, float* __restrict__ statsFL)
{
    const int t = threadIdx.x;
    if (t < 128) {
        float s = 0.f;
#pragma unroll
        for (int bin = 0; bin < SBINS; ++bin) s += statsPL[bin * 128 + t];
        statsFL[t] = s;
    }
}

// =====================================================================
// build point-major input records: xall[b][p][0..2]=coords, [3..66]=feats,
// [67]=pad (272 B record, float4-aligned)
// =====================================================================
__global__ __launch_bounds__(256) void build_xall(const float* __restrict__ coords,
                                                  const float* __restrict__ feats,
                                                  float* __restrict__ xall)
{
    const int tid = blockIdx.x * 256 + threadIdx.x;   // b*NPTS + p
    const int b = tid >> 13, p = tid & (NPTS - 1);
    const float* cb = coords + (size_t)b * 3 * NPTS;
    const float* fb = feats + (size_t)b * CFEAT * NPTS;
    float* xp = xall + (size_t)tid * 68;
    xp[0] = cb[p]; xp[1] = cb[NPTS + p]; xp[2] = cb[2 * NPTS + p];
#pragma unroll
    for (int c = 0; c < CFEAT; ++c) xp[3 + c] = fb[c * NPTS + p];
    xp[67] = 0.f;
}

// =====================================================================
// FPS v5: 1 block/batch, 256 threads, 32 pts/thread.
//  - __launch_bounds__(256, 1): fps runs 8 blocks on 256 CUs (1 wave/
//    SIMD), so cap VGPRs at the 1-wave budget (~512). R0's plain
//    launch_bounds(256) allocated only 84 VGPRs -- too few for the
//    128-float X/Y/Z/mind working set, forcing AGPR/LDS round trips.
//  - distance math in packed fp32 pairs (v_pk_add/mul_f32, VOP3P):
//    halves VALU issue for sub/mul/add. Per-element IEEE RN identical
//    to scalar; `#pragma clang fp contract(off)` blocks fma fusion so
//    ((dx*dx+dy*dy)+dz*dz) still matches numpy bitwise. Tie-break
//    (ascending global index, strict >) preserved exactly.
//  - reduce: R0's proven u64-packed 6-step __shfl_xor chain, one
//    barrier/iter, 4-slot double-buffered cross-wave combine.
// =====================================================================
__global__ __launch_bounds__(256, 1) void fps_kernel(const float* __restrict__ coords,
                                                     int* __restrict__ cidx)
{
#pragma clang fp contract(off)
    extern __shared__ float smem[];
    float* sx = smem;
    float* sy = smem + NPTS;
    float* sz = smem + 2 * NPTS;
    unsigned long long* wpack = (unsigned long long*)(smem + 3 * NPTS);  // [2][4]

    const int b = blockIdx.x;
    const int t = threadIdx.x;
    const float* cb = coords + (size_t)b * 3 * NPTS;

    v2f X2[16], Y2[16], Z2[16];
    float mind[32];
#pragma unroll
    for (int j = 0; j < 16; ++j) {
        const int p0 = t + (2 * j) * 256;
        const int p1 = t + (2 * j + 1) * 256;
        v2f xx, yy, zz;
        xx.x = cb[p0];             xx.y = cb[p1];
        yy.x = cb[NPTS + p0];      yy.y = cb[NPTS + p1];
        zz.x = cb[2 * NPTS + p0];  zz.y = cb[2 * NPTS + p1];
        sx[p0] = xx.x; sx[p1] = xx.y;
        sy[p0] = yy.x; sy[p1] = yy.y;
        sz[p0] = zz.x; sz[p1] = zz.y;
        X2[j] = xx; Y2[j] = yy; Z2[j] = zz;
        mind[2 * j] = 1e10f; mind[2 * j + 1] = 1e10f;
        // pin private copies in VGPR pairs: compiler may no longer fold
        // them into ds_reads of sx/sy/sz
        asm volatile("" : "+v"(X2[j]), "+v"(Y2[j]), "+v"(Z2[j]));
    }
    if (t == 0) cidx[b * NC] = 0;
    __syncthreads();

    int cur = 0;
    for (int it = 1; it < NC; ++it) {
        const float lx = sx[cur], ly = sy[cur], lz = sz[cur];  // broadcast
        v2f lxv, lyv, lzv;
        lxv.x = lx; lxv.y = lx;
        lyv.x = ly; lyv.y = ly;
        lzv.x = lz; lzv.y = lz;
        float bv = -1.0f; int bi = 0;
#pragma unroll
        for (int j = 0; j < 16; ++j) {
            v2f dx = X2[j] - lxv;          // v_pk_add_f32 (neg)
            v2f dy = Y2[j] - lyv;
            v2f dz = Z2[j] - lzv;
            v2f s0 = dx * dx;              // v_pk_mul_f32
            v2f s1 = dy * dy;
            v2f s2 = dz * dz;
            v2f d  = (s0 + s1) + s2;       // v_pk_add_f32 x2, no fma (contract off)
            float nm0 = fminf(mind[2 * j], d.x);
            mind[2 * j] = nm0;
            if (nm0 > bv) { bv = nm0; bi = t + (2 * j) * 256; }     // strict >: lowest idx
            float nm1 = fminf(mind[2 * j + 1], d.y);
            mind[2 * j + 1] = nm1;
            if (nm1 > bv) { bv = nm1; bi = t + (2 * j + 1) * 256; }
        }
        unsigned long long pack = ((unsigned long long)__float_as_uint(bv) << 32)
                                | (unsigned long long)(unsigned)(NPTS - 1 - bi);
#pragma unroll
        for (int o = 32; o > 0; o >>= 1) {
            unsigned long long other = __shfl_xor(pack, o);
            if (other > pack) pack = other;
        }
        unsigned long long* wp = wpack + (it & 1) * 4;     // double buffer
        if ((t & 63) == 0) wp[t >> 6] = pack;
        __syncthreads();
        unsigned long long best = wp[0];
#pragma unroll
        for (int w = 1; w < 4; ++w) {
            unsigned long long v = wp[w];
            if (v > best) best = v;
        }
        cur = NPTS - 1 - (int)(best & 0xffffffffu);
        if (t == 0) cidx[b * NC + it] = cur;
    }
}

// =====================================================================
// Ball query -> nidx + centers. EXPANDED d2 form (cn+pn)-2*cp, no fma.
// =====================================================================
__global__ __launch_bounds__(256) void bq_kernel(const float* __restrict__ coords,
                                                 const int* __restrict__ cidx,
                                                 int* __restrict__ nidx,
                                                 float* __restrict__ centers)
{
    const int s = blockIdx.x, b = blockIdx.y, t = threadIdx.x;
    __shared__ int s_idx[KNN];
    __shared__ int s_pref[9];
    __shared__ float s_c[3];
    __shared__ float s_cn;
    const float* cb = coords + (size_t)b * 3 * NPTS;
    if (t == 0) {
        int ci = cidx[b * NC + s];
        float cx = cb[ci], cy = cb[NPTS + ci], cz = cb[2 * NPTS + ci];
        s_c[0] = cx; s_c[1] = cy; s_c[2] = cz;
        s_cn = __fadd_rn(__fadd_rn(__fmul_rn(cx, cx), __fmul_rn(cy, cy)),
                         __fmul_rn(cz, cz));
    }
    __syncthreads();
    const float cx = s_c[0], cy = s_c[1], cz = s_c[2], cn = s_cn;
    const int base = t * 32;
    int cnt = 0;
    for (int j = 0; j < 32; ++j) {
        int p = base + j;
        float x = cb[p], y = cb[NPTS + p], z = cb[2 * NPTS + p];
        float pn = __fadd_rn(__fadd_rn(__fmul_rn(x, x), __fmul_rn(y, y)), __fmul_rn(z, z));
        float cp = __fadd_rn(__fadd_rn(__fmul_rn(cx, x), __fmul_rn(cy, y)), __fmul_rn(cz, z));
        float d2 = __fsub_rn(__fadd_rn(cn, pn), __fmul_rn(2.0f, cp));
        if (d2 < R2) ++cnt;
    }
    const int lane = t & 63, wid = t >> 6;
    int incl = cnt;
    for (int o = 1; o < 64; o <<= 1) {
        int v = __shfl_up(incl, o);
        if (lane >= o) incl += v;
    }
    if (lane == 63) s_pref[wid] = incl;
    __syncthreads();
    int ex = incl - cnt;
    for (int w = 0; w < wid; ++w) ex += s_pref[w];
    if (t == 255) s_pref[8] = ex + cnt;
    if (ex < KNN && cnt > 0) {
        int slot = ex;
        for (int j = 0; j < 32 && slot < KNN; ++j) {
            int p = base + j;
            float x = cb[p], y = cb[NPTS + p], z = cb[2 * NPTS + p];
            float pn = __fadd_rn(__fadd_rn(__fmul_rn(x, x), __fmul_rn(y, y)), __fmul_rn(z, z));
            float cp = __fadd_rn(__fadd_rn(__fmul_rn(cx, x), __fmul_rn(cy, y)), __fmul_rn(cz, z));
            float d2 = __fsub_rn(__fadd_rn(cn, pn), __fmul_rn(2.0f, cp));
            if (d2 < R2) { s_idx[slot] = p; ++slot; }
        }
    }
    __syncthreads();
    const int total = s_pref[8];
    if (t < KNN) {
        int v = (total == 0) ? 0 : ((t < total) ? s_idx[t] : s_idx[0]);
        nidx[(b * NC + s) * KNN + t] = v;
    }
    if (t < 3) centers[(b * NC + s) * 3 + t] = s_c[t];
}

// =====================================================================
// Layer 1: block = 64 cols x 4 out-chunks of 16. Gather staged in LDS
// xs[68][64] fp32; per-thread state is only acc[16] (no spill).
// =====================================================================
__global__ __launch_bounds__(256) void l1_kernel(const float* __restrict__ xall,
                                                 const int* __restrict__ nidx,
                                                 const float* __restrict__ centers,
                                                 const float* __restrict__ wt,
                                                 const float* __restrict__ b0,
                                                 float* __restrict__ Y,
                                                 float* __restrict__ statsPL)
{
    __shared__ float sw[67 * 64 + 64];
    __shared__ float xs[68 * 64];
    __shared__ float s_sum[8], s_sq[8];
    const int b = blockIdx.y, t = threadIdx.x;
    const int col = t & 63, q = t >> 6;
    const int n = blockIdx.x * 64 + col;
    for (int i = t; i < 67 * 64; i += 256) sw[i] = wt[i];
    if (t < 64) sw[67 * 64 + t] = b0[t];
    if (t < 8) { s_sum[t] = 0.f; s_sq[t] = 0.f; }
    const int s = n >> 5, k = n & 31;
    const int p = nidx[(b * NC + s) * KNN + k];
    const float4* xp4 = (const float4*)(xall + (size_t)(b * NPTS + p) * 68);
    const float* cc = centers + (size_t)(b * NC + s) * 3;
#pragma unroll
    for (int r = 0; r < 4; ++r) {
        float4 v = xp4[q * 4 + r];
        int ch = (q * 4 + r) * 4;
        if (ch == 0) { v.x -= cc[0]; v.y -= cc[1]; v.z -= cc[2]; }
        xs[(ch + 0) * 64 + col] = v.x;
        xs[(ch + 1) * 64 + col] = v.y;
        xs[(ch + 2) * 64 + col] = v.z;
        xs[(ch + 3) * 64 + col] = v.w;
    }
    if (q == 3) {
        float4 v = xp4[16];
        xs[64 * 64 + col] = v.x;
        xs[65 * 64 + col] = v.y;
        xs[66 * 64 + col] = v.z;
        xs[67 * 64 + col] = v.w;
    }
    __syncthreads();
    float acc[16];
#pragma unroll
    for (int o = 0; o < 16; ++o) acc[o] = sw[67 * 64 + q * 16 + o];
    for (int i = 0; i < 67; ++i) {
        float xv = xs[i * 64 + col];
        const float* wr = sw + i * 64 + q * 16;
#pragma unroll
        for (int o = 0; o < 16; ++o) acc[o] = fmaf(wr[o], xv, acc[o]);
    }
    float* yb = Y + (size_t)b * 64 * NSCOL + n;
#pragma unroll
    for (int o = 0; o < 16; ++o) yb[(size_t)(q * 16 + o) * NSCOL] = acc[o];
#pragma unroll
    for (int g = 0; g < 2; ++g) {
        float sv = 0.f, sq = 0.f;
#pragma unroll
        for (int j = 0; j < 8; ++j) { float vv = acc[g * 8 + j]; sv += vv; sq = fmaf(vv, vv, sq); }
#pragma unroll
        for (int o = 32; o > 0; o >>= 1) { sv += __shfl_xor(sv, o); sq += __shfl_xor(sq, o); }
        if ((t & 63) == 0) { atomicAdd(&s_sum[q * 2 + g], sv); atomicAdd(&s_sq[q * 2 + g], sq); }
    }
    __syncthreads();
    if (t < 16) {
        const int bin = blockIdx.x & (SBINS - 1);
        const int g = t >> 1, kk = t & 1;
        atomicAdd(&statsPL[bin * 128 + (b * 8 + g) * 2 + kk], kk ? s_sq[g] : s_sum[g]);
    }
}

// =====================================================================
// Layer 2: in-place, block = 64 cols x 4 out-chunks of 16.
// =====================================================================
__global__ __launch_bounds__(256) void l2_kernel(const float* __restrict__ wt1,
                                                 const float* __restrict__ b1,
                                                 const float* __restrict__ g0,
                                                 const float* __restrict__ be0,
                                                 const float* __restrict__ statsF_in,
                                                 float* __restrict__ statsPL,
                                                 float* __restrict__ Y)
{
    __shared__ float sw[64 * 64 + 64];
    __shared__ float xs[64 * 64];
    __shared__ float sA[64], sB[64];
    __shared__ float s_sum[8], s_sq[8];
    const int b = blockIdx.y, t = threadIdx.x;
    const int col = t & 63, q = t >> 6;
    const int n = blockIdx.x * 64 + col;
    for (int i = t; i < 64 * 64; i += 256) sw[i] = wt1[i];
    if (t < 64) {
        sw[64 * 64 + t] = b1[t];
        const int g = t >> 3;
        const float inv = 1.0f / (8.0f * NSCOL);
        float mu = statsF_in[(b * 8 + g) * 2 + 0] * inv;
        float var = statsF_in[(b * 8 + g) * 2 + 1] * inv - mu * mu;
        float A = (1.0f / sqrtf(var + GN_EPS)) * g0[t];
        sA[t] = A; sB[t] = be0[t] - mu * A;
    }
    if (t < 8) { s_sum[t] = 0.f; s_sq[t] = 0.f; }
    __syncthreads();
    float* yb = Y + (size_t)b * 64 * NSCOL + n;
#pragma unroll
    for (int r = 0; r < 16; ++r) {
        int i = q * 16 + r;
        float raw = yb[(size_t)i * NSCOL];
        float v = fmaf(raw, sA[i], sB[i]);
        xs[i * 64 + col] = v * __builtin_amdgcn_rcpf(1.0f + __expf(-v));
    }
    __syncthreads();
    float acc[16];
#pragma unroll
    for (int o = 0; o < 16; ++o) acc[o] = sw[64 * 64 + q * 16 + o];
    for (int i = 0; i < 64; ++i) {
        float xv = xs[i * 64 + col];
        const float* wr = sw + i * 64 + q * 16;
#pragma unroll
        for (int o = 0; o < 16; ++o) acc[o] = fmaf(wr[o], xv, acc[o]);
    }
#pragma unroll
    for (int o = 0; o < 16; ++o) yb[(size_t)(q * 16 + o) * NSCOL] = acc[o];
#pragma unroll
    for (int g = 0; g < 2; ++g) {
        float sv = 0.f, sq = 0.f;
#pragma unroll
        for (int j = 0; j < 8; ++j) { float vv = acc[g * 8 + j]; sv += vv; sq = fmaf(vv, vv, sq); }
#pragma unroll
        for (int o = 32; o > 0; o >>= 1) { sv += __shfl_xor(sv, o); sq += __shfl_xor(sq, o); }
        if ((t & 63) == 0) { atomicAdd(&s_sum[q * 2 + g], sv); atomicAdd(&s_sq[q * 2 + g], sq); }
    }
    __syncthreads();
    if (t < 16) {
        const int bin = blockIdx.x & (SBINS - 1);
        const int g = t >> 1, kk = t & 1;
        atomicAdd(&statsPL[bin * 128 + (b * 8 + g) * 2 + kk], kk ? s_sq[g] : s_sum[g]);
    }
}

// =====================================================================
// Layer 3: in-place, block = 64 cols x 4 out-chunks of 32 (128 out).
// Output bf16 pair-packed into the same 256B/col footprint.
// =====================================================================
__global__ __launch_bounds__(256) void l3_kernel(const float* __restrict__ wt2,
                                                 const float* __restrict__ b2,
                                                 const float* __restrict__ g1,
                                                 const float* __restrict__ be1,
                                                 const float* __restrict__ statsF_in,
                                                 float* __restrict__ statsPL,
                                                 float* __restrict__ Y)
{
    __shared__ float sw[64 * 128 + 128];
    __shared__ float xs[64 * 64];
    __shared__ float sA[64], sB[64];
    __shared__ float s_sum[8], s_sq[8];
    const int b = blockIdx.y, t = threadIdx.x;
    const int col = t & 63, q = t >> 6;
    const int n = blockIdx.x * 64 + col;
    for (int i = t; i < 64 * 128; i += 256) sw[i] = wt2[i];
    if (t < 128) sw[64 * 128 + t] = b2[t];
    if (t < 64) {
        const int g = t >> 3;
        const float inv = 1.0f / (8.0f * NSCOL);
        float mu = statsF_in[(b * 8 + g) * 2 + 0] * inv;
        float var = statsF_in[(b * 8 + g) * 2 + 1] * inv - mu * mu;
        float A = (1.0f / sqrtf(var + GN_EPS)) * g1[t];
        sA[t] = A; sB[t] = be1[t] - mu * A;
    }
    if (t < 8) { s_sum[t] = 0.f; s_sq[t] = 0.f; }
    __syncthreads();
    float* yb = Y + (size_t)b * 64 * NSCOL + n;
#pragma unroll
    for (int r = 0; r < 16; ++r) {
        int i = q * 16 + r;
        float raw = yb[(size_t)i * NSCOL];
        float v = fmaf(raw, sA[i], sB[i]);
        xs[i * 64 + col] = v * __builtin_amdgcn_rcpf(1.0f + __expf(-v));
    }
    __syncthreads();
    float acc[32];
#pragma unroll
    for (int o = 0; o < 32; ++o) acc[o] = sw[64 * 128 + q * 32 + o];
    for (int i = 0; i < 64; ++i) {
        float xv = xs[i * 64 + col];
        const float* wr = sw + i * 128 + q * 32;
#pragma unroll
        for (int o = 0; o < 32; ++o) acc[o] = fmaf(wr[o], xv, acc[o]);
    }
#pragma unroll
    for (int g = 0; g < 2; ++g) {
        float sv = 0.f, sq = 0.f;
#pragma unroll
        for (int j = 0; j < 16; ++j) { float vv = acc[g * 16 + j]; sv += vv; sq = fmaf(vv, vv, sq); }
#pragma unroll
        for (int o = 32; o > 0; o >>= 1) { sv += __shfl_xor(sv, o); sq += __shfl_xor(sq, o); }
        if ((t & 63) == 0) { atomicAdd(&s_sum[q * 2 + g], sv); atomicAdd(&s_sq[q * 2 + g], sq); }
    }
    unsigned* yu = (unsigned*)yb;
#pragma unroll
    for (int j = 0; j < 16; ++j) {
        unsigned u = f2bf(acc[2 * j]) | (f2bf(acc[2 * j + 1]) << 16);
        yu[(size_t)(q * 16 + j) * NSCOL] = u;
    }
    __syncthreads();
    if (t < 16) {
        const int bin = blockIdx.x & (SBINS - 1);
        const int g = t >> 1, kk = t & 1;
        atomicAdd(&statsPL[bin * 128 + (b * 8 + g) * 2 + kk], kk ? s_sq[g] : s_sum[g]);
    }
}

// =====================================================================
// Finalize: GN3 + SiLU + max over K. Thread per (b, channel-PAIR, s).
// =====================================================================
__global__ __launch_bounds__(256) void fin_kernel(const unsigned* __restrict__ Yu,
                                                  const float* __restrict__ g2,
                                                  const float* __restrict__ be2,
                                                  const float* __restrict__ stats,
                                                  float* __restrict__ out)
{
    const int tid = blockIdx.x * 256 + threadIdx.x;
    const int s = tid & (NC - 1);
    const int cp = (tid >> 11) & 63;
    const int b = tid >> 17;
    const int g = cp >> 3;
    const float inv = 1.0f / (16.0f * NSCOL);
    float mu = stats[(b * 8 + g) * 2 + 0] * inv;
    float var = stats[(b * 8 + g) * 2 + 1] * inv - mu * mu;
    float rs = 1.0f / sqrtf(var + GN_EPS);
    const int c0 = cp * 2, c1 = c0 + 1;
    float A0 = rs * g2[c0], B0 = be2[c0] - mu * A0;
    float A1 = rs * g2[c1], B1 = be2[c1] - mu * A1;
    const unsigned* yb = Yu + (size_t)(b * 64 + cp) * NSCOL + s * KNN;
    float m0 = -INFINITY, m1 = -INFINITY;
#pragma unroll
    for (int qq = 0; qq < 8; ++qq) {
        uint4 v = ((const uint4*)yb)[qq];
        unsigned uu[4] = {v.x, v.y, v.z, v.w};
#pragma unroll
        for (int r = 0; r < 4; ++r) {
            float f0 = __uint_as_float(uu[r] << 16);
            float f1 = __uint_as_float(uu[r] & 0xffff0000u);
            float v0 = fmaf(f0, A0, B0);
            v0 = v0 * __builtin_amdgcn_rcpf(1.0f + __expf(-v0));
            m0 = fmaxf(m0, v0);
            float v1 = fmaf(f1, A1, B1);
            v1 = v1 * __builtin_amdgcn_rcpf(1.0f + __expf(-v1));
            m1 = fmaxf(m1, v1);
        }
    }
    out[(size_t)(b * 128 + c0) * NC + s] = m0;
    out[(size_t)(b * 128 + c1) * NC + s] = m1;
}

// =====================================================================
extern "C" void kernel_launch(void* const* d_in, const int* in_sizes, int n_in,
                              void* d_out, int out_size, void* d_ws, size_t ws_size,
                              hipStream_t stream)
{
    if (ws_size < WS_NEEDED) return;

    const float* coords = (const float*)d_in[0];
    const float* feats  = (const float*)d_in[1];
    const float* w0  = (const float*)d_in[2];
    const float* b0  = (const float*)d_in[3];
    const float* g0  = (const float*)d_in[4];
    const float* be0 = (const float*)d_in[5];
    const float* w1  = (const float*)d_in[6];
    const float* b1  = (const float*)d_in[7];
    const float* g1  = (const float*)d_in[8];
    const float* be1 = (const float*)d_in[9];
    const float* w2  = (const float*)d_in[10];
    const float* b2  = (const float*)d_in[11];
    const float* g2  = (const float*)d_in[12];
    const float* be2 = (const float*)d_in[13];
    float* out = (float*)d_out;

    char* ws = (char*)d_ws;
    int*   cidx    = (int*)(ws + OFF_CIDX);
    int*   nidx    = (int*)(ws + OFF_NIDX);
    float* centers = (float*)(ws + OFF_CENT);
    float* statsP  = (float*)(ws + OFF_STATSP);   // [3][SBINS][128]
    float* statsF  = (float*)(ws + OFF_STATSF);   // [3][128]
    float* wt      = (float*)(ws + OFF_WT);
    float* xall    = (float*)(ws + OFF_XALL);
    float* Ybuf    = (float*)(ws + OFF_Y);

    prep_kernel<<<48, 256, 0, stream>>>(w0, w1, w2, statsP, statsF, wt);
    build_xall<<<(BATCH * NPTS) / 256, 256, 0, stream>>>(coords, feats, xall);
    // dynamic LDS: 3*NPTS floats (coords) + 8 u64 packs
    fps_kernel<<<BATCH, 256, 3 * NPTS * 4 + 64, stream>>>(coords, cidx);
    bq_kernel<<<dim3(NC, BATCH), 256, 0, stream>>>(coords, cidx, nidx, centers);

    const dim3 lgrid(NSCOL / 64, BATCH);
    l1_kernel<<<lgrid, 256, 0, stream>>>(xall, nidx, centers, wt, b0, Ybuf, statsP);
    reduce_stats<<<1, 128, 0, stream>>>(statsP, statsF);
    l2_kernel<<<lgrid, 256, 0, stream>>>(wt + 4288, b1, g0, be0,
                                         statsF, statsP + SBINS * 128, Ybuf);
    reduce_stats<<<1, 128, 0, stream>>>(statsP + SBINS * 128, statsF + 128);
    l3_kernel<<<lgrid, 256, 0, stream>>>(wt + 8384, b2, g1, be1,
                                         statsF + 128, statsP + 2 * SBINS * 128, Ybuf);
    reduce_stats<<<1, 128, 0, stream>>>(statsP + 2 * SBINS * 128, statsF + 256);
    fin_kernel<<<(BATCH * 64 * NC) / 256, 256, 0, stream>>>(
        (const unsigned*)Ybuf, g2, be2, statsF + 256, out);
    (void)in_sizes; (void)n_in; (void)out_size;
}

// Round 4
// 2908.778 us; speedup vs baseline: 1.1217x; 1.0223x over previous
//
#include <hip/hip_runtime.h>
#include <math.h>

#define BATCH 8
#define NPTS 8192
#define CFEAT 64
#define NC 2048           // S centers
#define KNN 32
#define NSCOL (NC*KNN)    // 65536 columns per batch
#define R2 0.0625f        // radius^2
#define GN_EPS 1e-5f
#define SBINS 32          // stat partial bins (cuts atomic contention 32x)

// ---- workspace layout (bytes) ----
#define OFF_CIDX   0ull
#define OFF_NIDX   65536ull
#define OFF_CENT   2162688ull
#define OFF_STATSP 2359296ull            // 3 layers x 32 bins x 128 fl = 49152 B
#define OFF_STATSF 2408448ull            // 3 x 128 fl = 1536 B
#define OFF_WT     2410496ull            // 16576 fl = 66304 B
#define OFF_XALL   4194304ull            // 17,825,792 B
#define OFF_Y      23068672ull           // 134,217,728 B
#define WS_NEEDED  (OFF_Y + 8ull*64*NSCOL*4ull)   // 150 MiB

static __device__ __forceinline__ unsigned f2bf(float f) {
    unsigned u = __float_as_uint(f);
    return (u + 0x7fffu + ((u >> 16) & 1u)) >> 16;   // RNE, finite inputs
}

// ---- fused u64-key DPP max step: all-VALU, no readlane, no SALU ----
// partner = dpp(hi,lo); if (partner > mine) take partner.
// bound_ctrl=false + old=self: invalid-src lanes compare self>self -> keep.
// Compare is a single v_cmp_lt_u64 (vcc), take is 2 cndmask.
template<int CTRL>
static __device__ __forceinline__ void dppmax64(unsigned& hi, unsigned& lo) {
    unsigned phi = (unsigned)__builtin_amdgcn_update_dpp((int)hi, (int)hi,
                                                         CTRL, 0xf, 0xf, false);
    unsigned plo = (unsigned)__builtin_amdgcn_update_dpp((int)lo, (int)lo,
                                                         CTRL, 0xf, 0xf, false);
    unsigned long long mine   = ((unsigned long long)hi  << 32) | lo;
    unsigned long long theirs = ((unsigned long long)phi << 32) | plo;
    if (theirs > mine) { hi = phi; lo = plo; }
}

// =====================================================================
// prep: zero stat partials/finals; transpose weights to [i][o] layout.
// =====================================================================
__global__ void prep_kernel(const float* __restrict__ w0, const float* __restrict__ w1,
                            const float* __restrict__ w2, float* __restrict__ statsP,
                            float* __restrict__ statsF, float* __restrict__ wt)
{
    const int t = blockIdx.x * 256 + threadIdx.x;
    if (t < 3 * SBINS * 128) statsP[t] = 0.f;
    if (t < 384) statsF[t] = 0.f;
    if (t < 64 * 67) { int o = t / 67, i = t - o * 67; wt[i * 64 + o] = w0[t]; }
    if (t < 64 * 64) { int o = t >> 6, i = t & 63;     wt[4288 + i * 64 + o] = w1[t]; }
    if (t < 128 * 64){ int o = t >> 6, i = t & 63;     wt[8384 + i * 128 + o] = w2[t]; }
}

// =====================================================================
__global__ void reduce_stats(const float* __restrict__ statsPL, float* __restrict__ statsFL)
{
    const int t = threadIdx.x;
    if (t < 128) {
        float s = 0.f;
#pragma unroll
        for (int bin = 0; bin < SBINS; ++bin) s += statsPL[bin * 128 + t];
        statsFL[t] = s;
    }
}

// =====================================================================
// build point-major input records: xall[b][p][0..2]=coords, [3..66]=feats,
// [67]=pad (272 B record, float4-aligned)
// =====================================================================
__global__ __launch_bounds__(256) void build_xall(const float* __restrict__ coords,
                                                  const float* __restrict__ feats,
                                                  float* __restrict__ xall)
{
    const int tid = blockIdx.x * 256 + threadIdx.x;   // b*NPTS + p
    const int b = tid >> 13, p = tid & (NPTS - 1);
    const float* cb = coords + (size_t)b * 3 * NPTS;
    const float* fb = feats + (size_t)b * CFEAT * NPTS;
    float* xp = xall + (size_t)tid * 68;
    xp[0] = cb[p]; xp[1] = cb[NPTS + p]; xp[2] = cb[2 * NPTS + p];
#pragma unroll
    for (int c = 0; c < CFEAT; ++c) xp[3 + c] = fb[c * NPTS + p];
    xp[67] = 0.f;
}

// =====================================================================
// FPS v6 (resubmit of R3 -- container infra failure, no kernel change):
// R0 structure (scalar j-loop, 4-slot double-buffered cross-wave
// combine, one barrier/iter) with ONE change: the intra-wave reduce.
//   R0: 6-step __shfl_xor on a u64 pack = 12 DS-pipe ops in a 6-deep
//       dependent chain (~600-700 cy of LDS latency per iteration).
//   v6: 6-step DPP butterfly on the same u64 key (row_shr 1/2/4/8 +
//       row_bcast 15/31), each step = 2 v_mov_dpp + v_cmp_lt_u64 +
//       2 cndmask, all-VALU (~150 cy). Result lands in lane 63; that
//       lane writes the wave slot (R0 wrote from lane 0).
// DPP ctrl codes HW-verified by R1 (passed correctness). R1's perf loss
// came from two-phase readlane/scalar dance + coord-carry slots -- both
// absent here. Tie-break (lowest global index via NPTS-1-bi key) and
// no-contract fp32 distance math are bit-identical to R0.
// =====================================================================
__global__ __launch_bounds__(256, 1) void fps_kernel(const float* __restrict__ coords,
                                                     int* __restrict__ cidx)
{
    extern __shared__ float smem[];
    float* sx = smem;
    float* sy = smem + NPTS;
    float* sz = smem + 2 * NPTS;
    unsigned long long* wpack = (unsigned long long*)(smem + 3 * NPTS);  // [2][4]

    const int b = blockIdx.x;
    const int t = threadIdx.x;
    const float* cb = coords + (size_t)b * 3 * NPTS;

    float X[32], Y[32], Z[32], mind[32];
#pragma unroll
    for (int j = 0; j < 32; ++j) {
        int p = t + j * 256;
        X[j] = cb[p];
        Y[j] = cb[NPTS + p];
        Z[j] = cb[2 * NPTS + p];
        sx[p] = X[j]; sy[p] = Y[j]; sz[p] = Z[j];
        mind[j] = 1e10f;
        // pin private copies in VGPRs: compiler may no longer fold them
        // into ds_reads of sx/sy/sz
        asm volatile("" : "+v"(X[j]), "+v"(Y[j]), "+v"(Z[j]));
    }
    if (t == 0) cidx[b * NC] = 0;
    __syncthreads();

    int cur = 0;
    for (int it = 1; it < NC; ++it) {
        const float lx = sx[cur], ly = sy[cur], lz = sz[cur];  // broadcast
        float bv = -1.0f; int bi = 0;
#pragma unroll
        for (int j = 0; j < 32; ++j) {
            float dx = __fsub_rn(X[j], lx);
            float dy = __fsub_rn(Y[j], ly);
            float dz = __fsub_rn(Z[j], lz);
            float d  = __fadd_rn(__fadd_rn(__fmul_rn(dx, dx), __fmul_rn(dy, dy)),
                                 __fmul_rn(dz, dz));
            float nm = fminf(mind[j], d);
            mind[j] = nm;
            if (nm > bv) { bv = nm; bi = t + j * 256; }   // strict >: lowest idx
        }
        // ---- intra-wave reduce: 6-step all-VALU DPP butterfly on u64 key ----
        unsigned hi = __float_as_uint(bv);                 // bv >= 0: uint order == float order
        unsigned lo = (unsigned)(NPTS - 1 - bi);           // larger lo == smaller index
        dppmax64<0x111>(hi, lo);   // row_shr:1
        dppmax64<0x112>(hi, lo);   // row_shr:2
        dppmax64<0x114>(hi, lo);   // row_shr:4
        dppmax64<0x118>(hi, lo);   // row_shr:8  -> lane15 of each row16 has row max
        dppmax64<0x142>(hi, lo);   // row_bcast:15 -> lane31 has max(0..31), lane63 max(32..63)
        dppmax64<0x143>(hi, lo);   // row_bcast:31 -> lane63 has wave max
        unsigned long long pack = ((unsigned long long)hi << 32)
                                | (unsigned long long)lo;

        unsigned long long* wp = wpack + (it & 1) * 4;     // double buffer
        if ((t & 63) == 63) wp[t >> 6] = pack;             // winner is in lane 63
        __syncthreads();
        unsigned long long best = wp[0];
#pragma unroll
        for (int w = 1; w < 4; ++w) {
            unsigned long long v = wp[w];
            if (v > best) best = v;
        }
        cur = NPTS - 1 - (int)(best & 0xffffffffu);
        if (t == 0) cidx[b * NC + it] = cur;
    }
}

// =====================================================================
// Ball query -> nidx + centers. EXPANDED d2 form (cn+pn)-2*cp, no fma.
// =====================================================================
__global__ __launch_bounds__(256) void bq_kernel(const float* __restrict__ coords,
                                                 const int* __restrict__ cidx,
                                                 int* __restrict__ nidx,
                                                 float* __restrict__ centers)
{
    const int s = blockIdx.x, b = blockIdx.y, t = threadIdx.x;
    __shared__ int s_idx[KNN];
    __shared__ int s_pref[9];
    __shared__ float s_c[3];
    __shared__ float s_cn;
    const float* cb = coords + (size_t)b * 3 * NPTS;
    if (t == 0) {
        int ci = cidx[b * NC + s];
        float cx = cb[ci], cy = cb[NPTS + ci], cz = cb[2 * NPTS + ci];
        s_c[0] = cx; s_c[1] = cy; s_c[2] = cz;
        s_cn = __fadd_rn(__fadd_rn(__fmul_rn(cx, cx), __fmul_rn(cy, cy)),
                         __fmul_rn(cz, cz));
    }
    __syncthreads();
    const float cx = s_c[0], cy = s_c[1], cz = s_c[2], cn = s_cn;
    const int base = t * 32;
    int cnt = 0;
    for (int j = 0; j < 32; ++j) {
        int p = base + j;
        float x = cb[p], y = cb[NPTS + p], z = cb[2 * NPTS + p];
        float pn = __fadd_rn(__fadd_rn(__fmul_rn(x, x), __fmul_rn(y, y)), __fmul_rn(z, z));
        float cp = __fadd_rn(__fadd_rn(__fmul_rn(cx, x), __fmul_rn(cy, y)), __fmul_rn(cz, z));
        float d2 = __fsub_rn(__fadd_rn(cn, pn), __fmul_rn(2.0f, cp));
        if (d2 < R2) ++cnt;
    }
    const int lane = t & 63, wid = t >> 6;
    int incl = cnt;
    for (int o = 1; o < 64; o <<= 1) {
        int v = __shfl_up(incl, o);
        if (lane >= o) incl += v;
    }
    if (lane == 63) s_pref[wid] = incl;
    __syncthreads();
    int ex = incl - cnt;
    for (int w = 0; w < wid; ++w) ex += s_pref[w];
    if (t == 255) s_pref[8] = ex + cnt;
    if (ex < KNN && cnt > 0) {
        int slot = ex;
        for (int j = 0; j < 32 && slot < KNN; ++j) {
            int p = base + j;
            float x = cb[p], y = cb[NPTS + p], z = cb[2 * NPTS + p];
            float pn = __fadd_rn(__fadd_rn(__fmul_rn(x, x), __fmul_rn(y, y)), __fmul_rn(z, z));
            float cp = __fadd_rn(__fadd_rn(__fmul_rn(cx, x), __fmul_rn(cy, y)), __fmul_rn(cz, z));
            float d2 = __fsub_rn(__fadd_rn(cn, pn), __fmul_rn(2.0f, cp));
            if (d2 < R2) { s_idx[slot] = p; ++slot; }
        }
    }
    __syncthreads();
    const int total = s_pref[8];
    if (t < KNN) {
        int v = (total == 0) ? 0 : ((t < total) ? s_idx[t] : s_idx[0]);
        nidx[(b * NC + s) * KNN + t] = v;
    }
    if (t < 3) centers[(b * NC + s) * 3 + t] = s_c[t];
}

// =====================================================================
// Layer 1: block = 64 cols x 4 out-chunks of 16. Gather staged in LDS
// xs[68][64] fp32; per-thread state is only acc[16] (no spill).
// =====================================================================
__global__ __launch_bounds__(256) void l1_kernel(const float* __restrict__ xall,
                                                 const int* __restrict__ nidx,
                                                 const float* __restrict__ centers,
                                                 const float* __restrict__ wt,
                                                 const float* __restrict__ b0,
                                                 float* __restrict__ Y,
                                                 float* __restrict__ statsPL)
{
    __shared__ float sw[67 * 64 + 64];
    __shared__ float xs[68 * 64];
    __shared__ float s_sum[8], s_sq[8];
    const int b = blockIdx.y, t = threadIdx.x;
    const int col = t & 63, q = t >> 6;
    const int n = blockIdx.x * 64 + col;
    for (int i = t; i < 67 * 64; i += 256) sw[i] = wt[i];
    if (t < 64) sw[67 * 64 + t] = b0[t];
    if (t < 8) { s_sum[t] = 0.f; s_sq[t] = 0.f; }
    const int s = n >> 5, k = n & 31;
    const int p = nidx[(b * NC + s) * KNN + k];
    const float4* xp4 = (const float4*)(xall + (size_t)(b * NPTS + p) * 68);
    const float* cc = centers + (size_t)(b * NC + s) * 3;
#pragma unroll
    for (int r = 0; r < 4; ++r) {
        float4 v = xp4[q * 4 + r];
        int ch = (q * 4 + r) * 4;
        if (ch == 0) { v.x -= cc[0]; v.y -= cc[1]; v.z -= cc[2]; }
        xs[(ch + 0) * 64 + col] = v.x;
        xs[(ch + 1) * 64 + col] = v.y;
        xs[(ch + 2) * 64 + col] = v.z;
        xs[(ch + 3) * 64 + col] = v.w;
    }
    if (q == 3) {
        float4 v = xp4[16];
        xs[64 * 64 + col] = v.x;
        xs[65 * 64 + col] = v.y;
        xs[66 * 64 + col] = v.z;
        xs[67 * 64 + col] = v.w;
    }
    __syncthreads();
    float acc[16];
#pragma unroll
    for (int o = 0; o < 16; ++o) acc[o] = sw[67 * 64 + q * 16 + o];
    for (int i = 0; i < 67; ++i) {
        float xv = xs[i * 64 + col];
        const float* wr = sw + i * 64 + q * 16;
#pragma unroll
        for (int o = 0; o < 16; ++o) acc[o] = fmaf(wr[o], xv, acc[o]);
    }
    float* yb = Y + (size_t)b * 64 * NSCOL + n;
#pragma unroll
    for (int o = 0; o < 16; ++o) yb[(size_t)(q * 16 + o) * NSCOL] = acc[o];
#pragma unroll
    for (int g = 0; g < 2; ++g) {
        float sv = 0.f, sq = 0.f;
#pragma unroll
        for (int j = 0; j < 8; ++j) { float vv = acc[g * 8 + j]; sv += vv; sq = fmaf(vv, vv, sq); }
#pragma unroll
        for (int o = 32; o > 0; o >>= 1) { sv += __shfl_xor(sv, o); sq += __shfl_xor(sq, o); }
        if ((t & 63) == 0) { atomicAdd(&s_sum[q * 2 + g], sv); atomicAdd(&s_sq[q * 2 + g], sq); }
    }
    __syncthreads();
    if (t < 16) {
        const int bin = blockIdx.x & (SBINS - 1);
        const int g = t >> 1, kk = t & 1;
        atomicAdd(&statsPL[bin * 128 + (b * 8 + g) * 2 + kk], kk ? s_sq[g] : s_sum[g]);
    }
}

// =====================================================================
// Layer 2: in-place, block = 64 cols x 4 out-chunks of 16.
// =====================================================================
__global__ __launch_bounds__(256) void l2_kernel(const float* __restrict__ wt1,
                                                 const float* __restrict__ b1,
                                                 const float* __restrict__ g0,
                                                 const float* __restrict__ be0,
                                                 const float* __restrict__ statsF_in,
                                                 float* __restrict__ statsPL,
                                                 float* __restrict__ Y)
{
    __shared__ float sw[64 * 64 + 64];
    __shared__ float xs[64 * 64];
    __shared__ float sA[64], sB[64];
    __shared__ float s_sum[8], s_sq[8];
    const int b = blockIdx.y, t = threadIdx.x;
    const int col = t & 63, q = t >> 6;
    const int n = blockIdx.x * 64 + col;
    for (int i = t; i < 64 * 64; i += 256) sw[i] = wt1[i];
    if (t < 64) {
        sw[64 * 64 + t] = b1[t];
        const int g = t >> 3;
        const float inv = 1.0f / (8.0f * NSCOL);
        float mu = statsF_in[(b * 8 + g) * 2 + 0] * inv;
        float var = statsF_in[(b * 8 + g) * 2 + 1] * inv - mu * mu;
        float A = (1.0f / sqrtf(var + GN_EPS)) * g0[t];
        sA[t] = A; sB[t] = be0[t] - mu * A;
    }
    if (t < 8) { s_sum[t] = 0.f; s_sq[t] = 0.f; }
    __syncthreads();
    float* yb = Y + (size_t)b * 64 * NSCOL + n;
#pragma unroll
    for (int r = 0; r < 16; ++r) {
        int i = q * 16 + r;
        float raw = yb[(size_t)i * NSCOL];
        float v = fmaf(raw, sA[i], sB[i]);
        xs[i * 64 + col] = v * __builtin_amdgcn_rcpf(1.0f + __expf(-v));
    }
    __syncthreads();
    float acc[16];
#pragma unroll
    for (int o = 0; o < 16; ++o) acc[o] = sw[64 * 64 + q * 16 + o];
    for (int i = 0; i < 64; ++i) {
        float xv = xs[i * 64 + col];
        const float* wr = sw + i * 64 + q * 16;
#pragma unroll
        for (int o = 0; o < 16; ++o) acc[o] = fmaf(wr[o], xv, acc[o]);
    }
#pragma unroll
    for (int o = 0; o < 16; ++o) yb[(size_t)(q * 16 + o) * NSCOL] = acc[o];
#pragma unroll
    for (int g = 0; g < 2; ++g) {
        float sv = 0.f, sq = 0.f;
#pragma unroll
        for (int j = 0; j < 8; ++j) { float vv = acc[g * 8 + j]; sv += vv; sq = fmaf(vv, vv, sq); }
#pragma unroll
        for (int o = 32; o > 0; o >>= 1) { sv += __shfl_xor(sv, o); sq += __shfl_xor(sq, o); }
        if ((t & 63) == 0) { atomicAdd(&s_sum[q * 2 + g], sv); atomicAdd(&s_sq[q * 2 + g], sq); }
    }
    __syncthreads();
    if (t < 16) {
        const int bin = blockIdx.x & (SBINS - 1);
        const int g = t >> 1, kk = t & 1;
        atomicAdd(&statsPL[bin * 128 + (b * 8 + g) * 2 + kk], kk ? s_sq[g] : s_sum[g]);
    }
}

// =====================================================================
// Layer 3: in-place, block = 64 cols x 4 out-chunks of 32 (128 out).
// Output bf16 pair-packed into the same 256B/col footprint.
// =====================================================================
__global__ __launch_bounds__(256) void l3_kernel(const float* __restrict__ wt2,
                                                 const float* __restrict__ b2,
                                                 const float* __restrict__ g1,
                                                 const float* __restrict__ be1,
                                                 const float* __restrict__ statsF_in,
                                                 float* __restrict__ statsPL,
                                                 float* __restrict__ Y)
{
    __shared__ float sw[64 * 128 + 128];
    __shared__ float xs[64 * 64];
    __shared__ float sA[64], sB[64];
    __shared__ float s_sum[8], s_sq[8];
    const int b = blockIdx.y, t = threadIdx.x;
    const int col = t & 63, q = t >> 6;
    const int n = blockIdx.x * 64 + col;
    for (int i = t; i < 64 * 128; i += 256) sw[i] = wt2[i];
    if (t < 128) sw[64 * 128 + t] = b2[t];
    if (t < 64) {
        const int g = t >> 3;
        const float inv = 1.0f / (8.0f * NSCOL);
        float mu = statsF_in[(b * 8 + g) * 2 + 0] * inv;
        float var = statsF_in[(b * 8 + g) * 2 + 1] * inv - mu * mu;
        float A = (1.0f / sqrtf(var + GN_EPS)) * g1[t];
        sA[t] = A; sB[t] = be1[t] - mu * A;
    }
    if (t < 8) { s_sum[t] = 0.f; s_sq[t] = 0.f; }
    __syncthreads();
    float* yb = Y + (size_t)b * 64 * NSCOL + n;
#pragma unroll
    for (int r = 0; r < 16; ++r) {
        int i = q * 16 + r;
        float raw = yb[(size_t)i * NSCOL];
        float v = fmaf(raw, sA[i], sB[i]);
        xs[i * 64 + col] = v * __builtin_amdgcn_rcpf(1.0f + __expf(-v));
    }
    __syncthreads();
    float acc[32];
#pragma unroll
    for (int o = 0; o < 32; ++o) acc[o] = sw[64 * 128 + q * 32 + o];
    for (int i = 0; i < 64; ++i) {
        float xv = xs[i * 64 + col];
        const float* wr = sw + i * 128 + q * 32;
#pragma unroll
        for (int o = 0; o < 32; ++o) acc[o] = fmaf(wr[o], xv, acc[o]);
    }
#pragma unroll
    for (int g = 0; g < 2; ++g) {
        float sv = 0.f, sq = 0.f;
#pragma unroll
        for (int j = 0; j < 16; ++j) { float vv = acc[g * 16 + j]; sv += vv; sq = fmaf(vv, vv, sq); }
#pragma unroll
        for (int o = 32; o > 0; o >>= 1) { sv += __shfl_xor(sv, o); sq += __shfl_xor(sq, o); }
        if ((t & 63) == 0) { atomicAdd(&s_sum[q * 2 + g], sv); atomicAdd(&s_sq[q * 2 + g], sq); }
    }
    unsigned* yu = (unsigned*)yb;
#pragma unroll
    for (int j = 0; j < 16; ++j) {
        unsigned u = f2bf(acc[2 * j]) | (f2bf(acc[2 * j + 1]) << 16);
        yu[(size_t)(q * 16 + j) * NSCOL] = u;
    }
    __syncthreads();
    if (t < 16) {
        const int bin = blockIdx.x & (SBINS - 1);
        const int g = t >> 1, kk = t & 1;
        atomicAdd(&statsPL[bin * 128 + (b * 8 + g) * 2 + kk], kk ? s_sq[g] : s_sum[g]);
    }
}

// =====================================================================
// Finalize: GN3 + SiLU + max over K. Thread per (b, channel-PAIR, s).
// =====================================================================
__global__ __launch_bounds__(256) void fin_kernel(const unsigned* __restrict__ Yu,
                                                  const float* __restrict__ g2,
                                                  const float* __restrict__ be2,
                                                  const float* __restrict__ stats,
                                                  float* __restrict__ out)
{
    const int tid = blockIdx.x * 256 + threadIdx.x;
    const int s = tid & (NC - 1);
    const int cp = (tid >> 11) & 63;
    const int b = tid >> 17;
    const int g = cp >> 3;
    const float inv = 1.0f / (16.0f * NSCOL);
    float mu = stats[(b * 8 + g) * 2 + 0] * inv;
    float var = stats[(b * 8 + g) * 2 + 1] * inv - mu * mu;
    float rs = 1.0f / sqrtf(var + GN_EPS);
    const int c0 = cp * 2, c1 = c0 + 1;
    float A0 = rs * g2[c0], B0 = be2[c0] - mu * A0;
    float A1 = rs * g2[c1], B1 = be2[c1] - mu * A1;
    const unsigned* yb = Yu + (size_t)(b * 64 + cp) * NSCOL + s * KNN;
    float m0 = -INFINITY, m1 = -INFINITY;
#pragma unroll
    for (int qq = 0; qq < 8; ++qq) {
        uint4 v = ((const uint4*)yb)[qq];
        unsigned uu[4] = {v.x, v.y, v.z, v.w};
#pragma unroll
        for (int r = 0; r < 4; ++r) {
            float f0 = __uint_as_float(uu[r] << 16);
            float f1 = __uint_as_float(uu[r] & 0xffff0000u);
            float v0 = fmaf(f0, A0, B0);
            v0 = v0 * __builtin_amdgcn_rcpf(1.0f + __expf(-v0));
            m0 = fmaxf(m0, v0);
            float v1 = fmaf(f1, A1, B1);
            v1 = v1 * __builtin_amdgcn_rcpf(1.0f + __expf(-v1));
            m1 = fmaxf(m1, v1);
        }
    }
    out[(size_t)(b * 128 + c0) * NC + s] = m0;
    out[(size_t)(b * 128 + c1) * NC + s] = m1;
}

// =====================================================================
extern "C" void kernel_launch(void* const* d_in, const int* in_sizes, int n_in,
                              void* d_out, int out_size, void* d_ws, size_t ws_size,
                              hipStream_t stream)
{
    if (ws_size < WS_NEEDED) return;

    const float* coords = (const float*)d_in[0];
    const float* feats  = (const float*)d_in[1];
    const float* w0  = (const float*)d_in[2];
    const float* b0  = (const float*)d_in[3];
    const float* g0  = (const float*)d_in[4];
    const float* be0 = (const float*)d_in[5];
    const float* w1  = (const float*)d_in[6];
    const float* b1  = (const float*)d_in[7];
    const float* g1  = (const float*)d_in[8];
    const float* be1 = (const float*)d_in[9];
    const float* w2  = (const float*)d_in[10];
    const float* b2  = (const float*)d_in[11];
    const float* g2  = (const float*)d_in[12];
    const float* be2 = (const float*)d_in[13];
    float* out = (float*)d_out;

    char* ws = (char*)d_ws;
    int*   cidx    = (int*)(ws + OFF_CIDX);
    int*   nidx    = (int*)(ws + OFF_NIDX);
    float* centers = (float*)(ws + OFF_CENT);
    float* statsP  = (float*)(ws + OFF_STATSP);   // [3][SBINS][128]
    float* statsF  = (float*)(ws + OFF_STATSF);   // [3][128]
    float* wt      = (float*)(ws + OFF_WT);
    float* xall    = (float*)(ws + OFF_XALL);
    float* Ybuf    = (float*)(ws + OFF_Y);

    prep_kernel<<<48, 256, 0, stream>>>(w0, w1, w2, statsP, statsF, wt);
    build_xall<<<(BATCH * NPTS) / 256, 256, 0, stream>>>(coords, feats, xall);
    // dynamic LDS: 3*NPTS floats (coords) + 8 u64 packs
    fps_kernel<<<BATCH, 256, 3 * NPTS * 4 + 64, stream>>>(coords, cidx);
    bq_kernel<<<dim3(NC, BATCH), 256, 0, stream>>>(coords, cidx, nidx, centers);

    const dim3 lgrid(NSCOL / 64, BATCH);
    l1_kernel<<<lgrid, 256, 0, stream>>>(xall, nidx, centers, wt, b0, Ybuf, statsP);
    reduce_stats<<<1, 128, 0, stream>>>(statsP, statsF);
    l2_kernel<<<lgrid, 256, 0, stream>>>(wt + 4288, b1, g0, be0,
                                         statsF, statsP + SBINS * 128, Ybuf);
    reduce_stats<<<1, 128, 0, stream>>>(statsP + SBINS * 128, statsF + 128);
    l3_kernel<<<lgrid, 256, 0, stream>>>(wt + 8384, b2, g1, be1,
                                         statsF + 128, statsP + 2 * SBINS * 128, Ybuf);
    reduce_stats<<<1, 128, 0, stream>>>(statsP + 2 * SBINS * 128, statsF + 256);
    fin_kernel<<<(BATCH * 64 * NC) / 256, 256, 0, stream>>>(
        (const unsigned*)Ybuf, g2, be2, statsF + 256, out);
    (void)in_sizes; (void)n_in; (void)out_size;
}

// Round 5
// 2757.525 us; speedup vs baseline: 1.1832x; 1.0549x over previous
//
#include <hip/hip_runtime.h>
#include <math.h>

#define BATCH 8
#define NPTS 8192
#define CFEAT 64
#define NC 2048           // S centers
#define KNN 32
#define NSCOL (NC*KNN)    // 65536 columns per batch
#define R2 0.0625f        // radius^2
#define GN_EPS 1e-5f
#define SBINS 32          // stat partial bins (cuts atomic contention 32x)

// ---- workspace layout (bytes) ----
#define OFF_CIDX   0ull
#define OFF_NIDX   65536ull
#define OFF_CENT   2162688ull
#define OFF_STATSP 2359296ull            // 3 layers x 32 bins x 128 fl = 49152 B
#define OFF_STATSF 2408448ull            // 3 x 128 fl = 1536 B
#define OFF_WT     2410496ull            // 16576 fl = 66304 B
#define OFF_XALL   4194304ull            // 17,825,792 B
#define OFF_Y      23068672ull           // 134,217,728 B
#define WS_NEEDED  (OFF_Y + 8ull*64*NSCOL*4ull)   // 150 MiB

static __device__ __forceinline__ unsigned f2bf(float f) {
    unsigned u = __float_as_uint(f);
    return (u + 0x7fffu + ((u >> 16) & 1u)) >> 16;   // RNE, finite inputs
}

// ---- fused u64-key DPP max step: all-VALU, no readlane, no SALU ----
// partner = dpp(hi,lo); if (partner > mine) take partner.
// bound_ctrl=false + old=self: invalid-src lanes compare self>self -> keep.
template<int CTRL>
static __device__ __forceinline__ void dppmax64(unsigned& hi, unsigned& lo) {
    unsigned phi = (unsigned)__builtin_amdgcn_update_dpp((int)hi, (int)hi,
                                                         CTRL, 0xf, 0xf, false);
    unsigned plo = (unsigned)__builtin_amdgcn_update_dpp((int)lo, (int)lo,
                                                         CTRL, 0xf, 0xf, false);
    unsigned long long mine   = ((unsigned long long)hi  << 32) | lo;
    unsigned long long theirs = ((unsigned long long)phi << 32) | plo;
    if (theirs > mine) { hi = phi; lo = plo; }
}

// =====================================================================
// prep: zero stat partials/finals; transpose weights to [i][o] layout.
// =====================================================================
__global__ void prep_kernel(const float* __restrict__ w0, const float* __restrict__ w1,
                            const float* __restrict__ w2, float* __restrict__ statsP,
                            float* __restrict__ statsF, float* __restrict__ wt)
{
    const int t = blockIdx.x * 256 + threadIdx.x;
    if (t < 3 * SBINS * 128) statsP[t] = 0.f;
    if (t < 384) statsF[t] = 0.f;
    if (t < 64 * 67) { int o = t / 67, i = t - o * 67; wt[i * 64 + o] = w0[t]; }
    if (t < 64 * 64) { int o = t >> 6, i = t & 63;     wt[4288 + i * 64 + o] = w1[t]; }
    if (t < 128 * 64){ int o = t >> 6, i = t & 63;     wt[8384 + i * 128 + o] = w2[t]; }
}

// =====================================================================
__global__ void reduce_stats(const float* __restrict__ statsPL, float* __restrict__ statsFL)
{
    const int t = threadIdx.x;
    if (t < 128) {
        float s = 0.f;
#pragma unroll
        for (int bin = 0; bin < SBINS; ++bin) s += statsPL[bin * 128 + t];
        statsFL[t] = s;
    }
}

// =====================================================================
// build point-major input records: xall[b][p][0..2]=coords, [3..66]=feats,
// [67]=pad (272 B record, float4-aligned)
// =====================================================================
__global__ __launch_bounds__(256) void build_xall(const float* __restrict__ coords,
                                                  const float* __restrict__ feats,
                                                  float* __restrict__ xall)
{
    const int tid = blockIdx.x * 256 + threadIdx.x;   // b*NPTS + p
    const int b = tid >> 13, p = tid & (NPTS - 1);
    const float* cb = coords + (size_t)b * 3 * NPTS;
    const float* fb = feats + (size_t)b * CFEAT * NPTS;
    float* xp = xall + (size_t)tid * 68;
    xp[0] = cb[p]; xp[1] = cb[NPTS + p]; xp[2] = cb[2 * NPTS + p];
#pragma unroll
    for (int c = 0; c < CFEAT; ++c) xp[3 + c] = fb[c * NPTS + p];
    xp[67] = 0.f;
}

// =====================================================================
// FPS v7: 512 threads/block (8 waves), 16 pts/thread.
// DIAGNOSIS from R4 counters: at 256 thr x 32 pts the private working
// set (X/Y/Z/mind = 128 fl) exceeds the ~100 VGPRs the allocator grants
// (VGPR_Count=100 even with launch_bounds(256,1)) -> AGPR/LDS shuttle
// ops dominate the j-loop (VALU issue ~1500 cy/iter vs ~700 clean).
// FIX: halve the per-thread footprint (64 fl fits in ~100 VGPRs) so the
// arrays are genuinely register-resident. Per-SIMD VALU issue work is
// unchanged (2 waves x 16 = 1 wave x 32), shuttle disappears, and
// 2 waves/SIMD hide latency. Reduce: same u64-key DPP butterfly
// (HW-verified R1/R4), now 8 double-buffered wave slots.
// Tie-break bit-identical: within-thread indices t+j*512 increase with
// j (strict > keeps lowest); cross-lane/wave key = (bv, NPTS-1-bi).
// No-contract fp32 distance matches numpy bitwise.
// =====================================================================
__global__ __launch_bounds__(512, 1) void fps_kernel(const float* __restrict__ coords,
                                                     int* __restrict__ cidx)
{
    extern __shared__ float smem[];
    float* sx = smem;
    float* sy = smem + NPTS;
    float* sz = smem + 2 * NPTS;
    unsigned long long* wpack = (unsigned long long*)(smem + 3 * NPTS);  // [2][8]

    const int b = blockIdx.x;
    const int t = threadIdx.x;
    const float* cb = coords + (size_t)b * 3 * NPTS;

    float X[16], Y[16], Z[16], mind[16];
#pragma unroll
    for (int j = 0; j < 16; ++j) {
        int p = t + j * 512;
        X[j] = cb[p];
        Y[j] = cb[NPTS + p];
        Z[j] = cb[2 * NPTS + p];
        sx[p] = X[j]; sy[p] = Y[j]; sz[p] = Z[j];
        mind[j] = 1e10f;
        // pin private copies in VGPRs: compiler may no longer fold them
        // into ds_reads of sx/sy/sz
        asm volatile("" : "+v"(X[j]), "+v"(Y[j]), "+v"(Z[j]));
    }
    if (t == 0) cidx[b * NC] = 0;
    __syncthreads();

    int cur = 0;
    for (int it = 1; it < NC; ++it) {
        const float lx = sx[cur], ly = sy[cur], lz = sz[cur];  // broadcast
        float bv = -1.0f; int bi = 0;
#pragma unroll
        for (int j = 0; j < 16; ++j) {
            float dx = __fsub_rn(X[j], lx);
            float dy = __fsub_rn(Y[j], ly);
            float dz = __fsub_rn(Z[j], lz);
            float d  = __fadd_rn(__fadd_rn(__fmul_rn(dx, dx), __fmul_rn(dy, dy)),
                                 __fmul_rn(dz, dz));
            float nm = fminf(mind[j], d);
            mind[j] = nm;
            if (nm > bv) { bv = nm; bi = t + j * 512; }   // strict >: lowest idx
        }
        // ---- intra-wave reduce: 6-step all-VALU DPP butterfly on u64 key ----
        unsigned hi = __float_as_uint(bv);                 // bv >= 0: uint order == float order
        unsigned lo = (unsigned)(NPTS - 1 - bi);           // larger lo == smaller index
        dppmax64<0x111>(hi, lo);   // row_shr:1
        dppmax64<0x112>(hi, lo);   // row_shr:2
        dppmax64<0x114>(hi, lo);   // row_shr:4
        dppmax64<0x118>(hi, lo);   // row_shr:8
        dppmax64<0x142>(hi, lo);   // row_bcast:15
        dppmax64<0x143>(hi, lo);   // row_bcast:31 -> lane63 has wave max
        unsigned long long pack = ((unsigned long long)hi << 32)
                                | (unsigned long long)lo;

        unsigned long long* wp = wpack + (it & 1) * 8;     // double buffer
        if ((t & 63) == 63) wp[t >> 6] = pack;             // winner is in lane 63
        __syncthreads();
        unsigned long long best = wp[0];
#pragma unroll
        for (int w = 1; w < 8; ++w) {
            unsigned long long v = wp[w];
            if (v > best) best = v;
        }
        cur = NPTS - 1 - (int)(best & 0xffffffffu);
        if (t == 0) cidx[b * NC + it] = cur;
    }
}

// =====================================================================
// Ball query -> nidx + centers. EXPANDED d2 form (cn+pn)-2*cp, no fma.
// =====================================================================
__global__ __launch_bounds__(256) void bq_kernel(const float* __restrict__ coords,
                                                 const int* __restrict__ cidx,
                                                 int* __restrict__ nidx,
                                                 float* __restrict__ centers)
{
    const int s = blockIdx.x, b = blockIdx.y, t = threadIdx.x;
    __shared__ int s_idx[KNN];
    __shared__ int s_pref[9];
    __shared__ float s_c[3];
    __shared__ float s_cn;
    const float* cb = coords + (size_t)b * 3 * NPTS;
    if (t == 0) {
        int ci = cidx[b * NC + s];
        float cx = cb[ci], cy = cb[NPTS + ci], cz = cb[2 * NPTS + ci];
        s_c[0] = cx; s_c[1] = cy; s_c[2] = cz;
        s_cn = __fadd_rn(__fadd_rn(__fmul_rn(cx, cx), __fmul_rn(cy, cy)),
                         __fmul_rn(cz, cz));
    }
    __syncthreads();
    const float cx = s_c[0], cy = s_c[1], cz = s_c[2], cn = s_cn;
    const int base = t * 32;
    int cnt = 0;
    for (int j = 0; j < 32; ++j) {
        int p = base + j;
        float x = cb[p], y = cb[NPTS + p], z = cb[2 * NPTS + p];
        float pn = __fadd_rn(__fadd_rn(__fmul_rn(x, x), __fmul_rn(y, y)), __fmul_rn(z, z));
        float cp = __fadd_rn(__fadd_rn(__fmul_rn(cx, x), __fmul_rn(cy, y)), __fmul_rn(cz, z));
        float d2 = __fsub_rn(__fadd_rn(cn, pn), __fmul_rn(2.0f, cp));
        if (d2 < R2) ++cnt;
    }
    const int lane = t & 63, wid = t >> 6;
    int incl = cnt;
    for (int o = 1; o < 64; o <<= 1) {
        int v = __shfl_up(incl, o);
        if (lane >= o) incl += v;
    }
    if (lane == 63) s_pref[wid] = incl;
    __syncthreads();
    int ex = incl - cnt;
    for (int w = 0; w < wid; ++w) ex += s_pref[w];
    if (t == 255) s_pref[8] = ex + cnt;
    if (ex < KNN && cnt > 0) {
        int slot = ex;
        for (int j = 0; j < 32 && slot < KNN; ++j) {
            int p = base + j;
            float x = cb[p], y = cb[NPTS + p], z = cb[2 * NPTS + p];
            float pn = __fadd_rn(__fadd_rn(__fmul_rn(x, x), __fmul_rn(y, y)), __fmul_rn(z, z));
            float cp = __fadd_rn(__fadd_rn(__fmul_rn(cx, x), __fmul_rn(cy, y)), __fmul_rn(cz, z));
            float d2 = __fsub_rn(__fadd_rn(cn, pn), __fmul_rn(2.0f, cp));
            if (d2 < R2) { s_idx[slot] = p; ++slot; }
        }
    }
    __syncthreads();
    const int total = s_pref[8];
    if (t < KNN) {
        int v = (total == 0) ? 0 : ((t < total) ? s_idx[t] : s_idx[0]);
        nidx[(b * NC + s) * KNN + t] = v;
    }
    if (t < 3) centers[(b * NC + s) * 3 + t] = s_c[t];
}

// =====================================================================
// Layer 1: block = 64 cols x 4 out-chunks of 16. Gather staged in LDS
// xs[68][64] fp32; per-thread state is only acc[16] (no spill).
// =====================================================================
__global__ __launch_bounds__(256) void l1_kernel(const float* __restrict__ xall,
                                                 const int* __restrict__ nidx,
                                                 const float* __restrict__ centers,
                                                 const float* __restrict__ wt,
                                                 const float* __restrict__ b0,
                                                 float* __restrict__ Y,
                                                 float* __restrict__ statsPL)
{
    __shared__ float sw[67 * 64 + 64];
    __shared__ float xs[68 * 64];
    __shared__ float s_sum[8], s_sq[8];
    const int b = blockIdx.y, t = threadIdx.x;
    const int col = t & 63, q = t >> 6;
    const int n = blockIdx.x * 64 + col;
    for (int i = t; i < 67 * 64; i += 256) sw[i] = wt[i];
    if (t < 64) sw[67 * 64 + t] = b0[t];
    if (t < 8) { s_sum[t] = 0.f; s_sq[t] = 0.f; }
    const int s = n >> 5, k = n & 31;
    const int p = nidx[(b * NC + s) * KNN + k];
    const float4* xp4 = (const float4*)(xall + (size_t)(b * NPTS + p) * 68);
    const float* cc = centers + (size_t)(b * NC + s) * 3;
#pragma unroll
    for (int r = 0; r < 4; ++r) {
        float4 v = xp4[q * 4 + r];
        int ch = (q * 4 + r) * 4;
        if (ch == 0) { v.x -= cc[0]; v.y -= cc[1]; v.z -= cc[2]; }
        xs[(ch + 0) * 64 + col] = v.x;
        xs[(ch + 1) * 64 + col] = v.y;
        xs[(ch + 2) * 64 + col] = v.z;
        xs[(ch + 3) * 64 + col] = v.w;
    }
    if (q == 3) {
        float4 v = xp4[16];
        xs[64 * 64 + col] = v.x;
        xs[65 * 64 + col] = v.y;
        xs[66 * 64 + col] = v.z;
        xs[67 * 64 + col] = v.w;
    }
    __syncthreads();
    float acc[16];
#pragma unroll
    for (int o = 0; o < 16; ++o) acc[o] = sw[67 * 64 + q * 16 + o];
    for (int i = 0; i < 67; ++i) {
        float xv = xs[i * 64 + col];
        const float* wr = sw + i * 64 + q * 16;
#pragma unroll
        for (int o = 0; o < 16; ++o) acc[o] = fmaf(wr[o], xv, acc[o]);
    }
    float* yb = Y + (size_t)b * 64 * NSCOL + n;
#pragma unroll
    for (int o = 0; o < 16; ++o) yb[(size_t)(q * 16 + o) * NSCOL] = acc[o];
#pragma unroll
    for (int g = 0; g < 2; ++g) {
        float sv = 0.f, sq = 0.f;
#pragma unroll
        for (int j = 0; j < 8; ++j) { float vv = acc[g * 8 + j]; sv += vv; sq = fmaf(vv, vv, sq); }
#pragma unroll
        for (int o = 32; o > 0; o >>= 1) { sv += __shfl_xor(sv, o); sq += __shfl_xor(sq, o); }
        if ((t & 63) == 0) { atomicAdd(&s_sum[q * 2 + g], sv); atomicAdd(&s_sq[q * 2 + g], sq); }
    }
    __syncthreads();
    if (t < 16) {
        const int bin = blockIdx.x & (SBINS - 1);
        const int g = t >> 1, kk = t & 1;
        atomicAdd(&statsPL[bin * 128 + (b * 8 + g) * 2 + kk], kk ? s_sq[g] : s_sum[g]);
    }
}

// =====================================================================
// Layer 2: in-place, block = 64 cols x 4 out-chunks of 16.
// =====================================================================
__global__ __launch_bounds__(256) void l2_kernel(const float* __restrict__ wt1,
                                                 const float* __restrict__ b1,
                                                 const float* __restrict__ g0,
                                                 const float* __restrict__ be0,
                                                 const float* __restrict__ statsF_in,
                                                 float* __restrict__ statsPL,
                                                 float* __restrict__ Y)
{
    __shared__ float sw[64 * 64 + 64];
    __shared__ float xs[64 * 64];
    __shared__ float sA[64], sB[64];
    __shared__ float s_sum[8], s_sq[8];
    const int b = blockIdx.y, t = threadIdx.x;
    const int col = t & 63, q = t >> 6;
    const int n = blockIdx.x * 64 + col;
    for (int i = t; i < 64 * 64; i += 256) sw[i] = wt1[i];
    if (t < 64) {
        sw[64 * 64 + t] = b1[t];
        const int g = t >> 3;
        const float inv = 1.0f / (8.0f * NSCOL);
        float mu = statsF_in[(b * 8 + g) * 2 + 0] * inv;
        float var = statsF_in[(b * 8 + g) * 2 + 1] * inv - mu * mu;
        float A = (1.0f / sqrtf(var + GN_EPS)) * g0[t];
        sA[t] = A; sB[t] = be0[t] - mu * A;
    }
    if (t < 8) { s_sum[t] = 0.f; s_sq[t] = 0.f; }
    __syncthreads();
    float* yb = Y + (size_t)b * 64 * NSCOL + n;
#pragma unroll
    for (int r = 0; r < 16; ++r) {
        int i = q * 16 + r;
        float raw = yb[(size_t)i * NSCOL];
        float v = fmaf(raw, sA[i], sB[i]);
        xs[i * 64 + col] = v * __builtin_amdgcn_rcpf(1.0f + __expf(-v));
    }
    __syncthreads();
    float acc[16];
#pragma unroll
    for (int o = 0; o < 16; ++o) acc[o] = sw[64 * 64 + q * 16 + o];
    for (int i = 0; i < 64; ++i) {
        float xv = xs[i * 64 + col];
        const float* wr = sw + i * 64 + q * 16;
#pragma unroll
        for (int o = 0; o < 16; ++o) acc[o] = fmaf(wr[o], xv, acc[o]);
    }
#pragma unroll
    for (int o = 0; o < 16; ++o) yb[(size_t)(q * 16 + o) * NSCOL] = acc[o];
#pragma unroll
    for (int g = 0; g < 2; ++g) {
        float sv = 0.f, sq = 0.f;
#pragma unroll
        for (int j = 0; j < 8; ++j) { float vv = acc[g * 8 + j]; sv += vv; sq = fmaf(vv, vv, sq); }
#pragma unroll
        for (int o = 32; o > 0; o >>= 1) { sv += __shfl_xor(sv, o); sq += __shfl_xor(sq, o); }
        if ((t & 63) == 0) { atomicAdd(&s_sum[q * 2 + g], sv); atomicAdd(&s_sq[q * 2 + g], sq); }
    }
    __syncthreads();
    if (t < 16) {
        const int bin = blockIdx.x & (SBINS - 1);
        const int g = t >> 1, kk = t & 1;
        atomicAdd(&statsPL[bin * 128 + (b * 8 + g) * 2 + kk], kk ? s_sq[g] : s_sum[g]);
    }
}

// =====================================================================
// Layer 3: in-place, block = 64 cols x 4 out-chunks of 32 (128 out).
// Output bf16 pair-packed into the same 256B/col footprint.
// =====================================================================
__global__ __launch_bounds__(256) void l3_kernel(const float* __restrict__ wt2,
                                                 const float* __restrict__ b2,
                                                 const float* __restrict__ g1,
                                                 const float* __restrict__ be1,
                                                 const float* __restrict__ statsF_in,
                                                 float* __restrict__ statsPL,
                                                 float* __restrict__ Y)
{
    __shared__ float sw[64 * 128 + 128];
    __shared__ float xs[64 * 64];
    __shared__ float sA[64], sB[64];
    __shared__ float s_sum[8], s_sq[8];
    const int b = blockIdx.y, t = threadIdx.x;
    const int col = t & 63, q = t >> 6;
    const int n = blockIdx.x * 64 + col;
    for (int i = t; i < 64 * 128; i += 256) sw[i] = wt2[i];
    if (t < 128) sw[64 * 128 + t] = b2[t];
    if (t < 64) {
        const int g = t >> 3;
        const float inv = 1.0f / (8.0f * NSCOL);
        float mu = statsF_in[(b * 8 + g) * 2 + 0] * inv;
        float var = statsF_in[(b * 8 + g) * 2 + 1] * inv - mu * mu;
        float A = (1.0f / sqrtf(var + GN_EPS)) * g1[t];
        sA[t] = A; sB[t] = be1[t] - mu * A;
    }
    if (t < 8) { s_sum[t] = 0.f; s_sq[t] = 0.f; }
    __syncthreads();
    float* yb = Y + (size_t)b * 64 * NSCOL + n;
#pragma unroll
    for (int r = 0; r < 16; ++r) {
        int i = q * 16 + r;
        float raw = yb[(size_t)i * NSCOL];
        float v = fmaf(raw, sA[i], sB[i]);
        xs[i * 64 + col] = v * __builtin_amdgcn_rcpf(1.0f + __expf(-v));
    }
    __syncthreads();
    float acc[32];
#pragma unroll
    for (int o = 0; o < 32; ++o) acc[o] = sw[64 * 128 + q * 32 + o];
    for (int i = 0; i < 64; ++i) {
        float xv = xs[i * 64 + col];
        const float* wr = sw + i * 128 + q * 32;
#pragma unroll
        for (int o = 0; o < 32; ++o) acc[o] = fmaf(wr[o], xv, acc[o]);
    }
#pragma unroll
    for (int g = 0; g < 2; ++g) {
        float sv = 0.f, sq = 0.f;
#pragma unroll
        for (int j = 0; j < 16; ++j) { float vv = acc[g * 16 + j]; sv += vv; sq = fmaf(vv, vv, sq); }
#pragma unroll
        for (int o = 32; o > 0; o >>= 1) { sv += __shfl_xor(sv, o); sq += __shfl_xor(sq, o); }
        if ((t & 63) == 0) { atomicAdd(&s_sum[q * 2 + g], sv); atomicAdd(&s_sq[q * 2 + g], sq); }
    }
    unsigned* yu = (unsigned*)yb;
#pragma unroll
    for (int j = 0; j < 16; ++j) {
        unsigned u = f2bf(acc[2 * j]) | (f2bf(acc[2 * j + 1]) << 16);
        yu[(size_t)(q * 16 + j) * NSCOL] = u;
    }
    __syncthreads();
    if (t < 16) {
        const int bin = blockIdx.x & (SBINS - 1);
        const int g = t >> 1, kk = t & 1;
        atomicAdd(&statsPL[bin * 128 + (b * 8 + g) * 2 + kk], kk ? s_sq[g] : s_sum[g]);
    }
}

// =====================================================================
// Finalize: GN3 + SiLU + max over K. Thread per (b, channel-PAIR, s).
// =====================================================================
__global__ __launch_bounds__(256) void fin_kernel(const unsigned* __restrict__ Yu,
                                                  const float* __restrict__ g2,
                                                  const float* __restrict__ be2,
                                                  const float* __restrict__ stats,
                                                  float* __restrict__ out)
{
    const int tid = blockIdx.x * 256 + threadIdx.x;
    const int s = tid & (NC - 1);
    const int cp = (tid >> 11) & 63;
    const int b = tid >> 17;
    const int g = cp >> 3;
    const float inv = 1.0f / (16.0f * NSCOL);
    float mu = stats[(b * 8 + g) * 2 + 0] * inv;
    float var = stats[(b * 8 + g) * 2 + 1] * inv - mu * mu;
    float rs = 1.0f / sqrtf(var + GN_EPS);
    const int c0 = cp * 2, c1 = c0 + 1;
    float A0 = rs * g2[c0], B0 = be2[c0] - mu * A0;
    float A1 = rs * g2[c1], B1 = be2[c1] - mu * A1;
    const unsigned* yb = Yu + (size_t)(b * 64 + cp) * NSCOL + s * KNN;
    float m0 = -INFINITY, m1 = -INFINITY;
#pragma unroll
    for (int qq = 0; qq < 8; ++qq) {
        uint4 v = ((const uint4*)yb)[qq];
        unsigned uu[4] = {v.x, v.y, v.z, v.w};
#pragma unroll
        for (int r = 0; r < 4; ++r) {
            float f0 = __uint_as_float(uu[r] << 16);
            float f1 = __uint_as_float(uu[r] & 0xffff0000u);
            float v0 = fmaf(f0, A0, B0);
            v0 = v0 * __builtin_amdgcn_rcpf(1.0f + __expf(-v0));
            m0 = fmaxf(m0, v0);
            float v1 = fmaf(f1, A1, B1);
            v1 = v1 * __builtin_amdgcn_rcpf(1.0f + __expf(-v1));
            m1 = fmaxf(m1, v1);
        }
    }
    out[(size_t)(b * 128 + c0) * NC + s] = m0;
    out[(size_t)(b * 128 + c1) * NC + s] = m1;
}

// =====================================================================
extern "C" void kernel_launch(void* const* d_in, const int* in_sizes, int n_in,
                              void* d_out, int out_size, void* d_ws, size_t ws_size,
                              hipStream_t stream)
{
    if (ws_size < WS_NEEDED) return;

    const float* coords = (const float*)d_in[0];
    const float* feats  = (const float*)d_in[1];
    const float* w0  = (const float*)d_in[2];
    const float* b0  = (const float*)d_in[3];
    const float* g0  = (const float*)d_in[4];
    const float* be0 = (const float*)d_in[5];
    const float* w1  = (const float*)d_in[6];
    const float* b1  = (const float*)d_in[7];
    const float* g1  = (const float*)d_in[8];
    const float* be1 = (const float*)d_in[9];
    const float* w2  = (const float*)d_in[10];
    const float* b2  = (const float*)d_in[11];
    const float* g2  = (const float*)d_in[12];
    const float* be2 = (const float*)d_in[13];
    float* out = (float*)d_out;

    char* ws = (char*)d_ws;
    int*   cidx    = (int*)(ws + OFF_CIDX);
    int*   nidx    = (int*)(ws + OFF_NIDX);
    float* centers = (float*)(ws + OFF_CENT);
    float* statsP  = (float*)(ws + OFF_STATSP);   // [3][SBINS][128]
    float* statsF  = (float*)(ws + OFF_STATSF);   // [3][128]
    float* wt      = (float*)(ws + OFF_WT);
    float* xall    = (float*)(ws + OFF_XALL);
    float* Ybuf    = (float*)(ws + OFF_Y);

    prep_kernel<<<48, 256, 0, stream>>>(w0, w1, w2, statsP, statsF, wt);
    build_xall<<<(BATCH * NPTS) / 256, 256, 0, stream>>>(coords, feats, xall);
    // dynamic LDS: 3*NPTS floats (coords) + 16 u64 packs (2x8 dbuf)
    fps_kernel<<<BATCH, 512, 3 * NPTS * 4 + 128, stream>>>(coords, cidx);
    bq_kernel<<<dim3(NC, BATCH), 256, 0, stream>>>(coords, cidx, nidx, centers);

    const dim3 lgrid(NSCOL / 64, BATCH);
    l1_kernel<<<lgrid, 256, 0, stream>>>(xall, nidx, centers, wt, b0, Ybuf, statsP);
    reduce_stats<<<1, 128, 0, stream>>>(statsP, statsF);
    l2_kernel<<<lgrid, 256, 0, stream>>>(wt + 4288, b1, g0, be0,
                                         statsF, statsP + SBINS * 128, Ybuf);
    reduce_stats<<<1, 128, 0, stream>>>(statsP + SBINS * 128, statsF + 128);
    l3_kernel<<<lgrid, 256, 0, stream>>>(wt + 8384, b2, g1, be1,
                                         statsF + 128, statsP + 2 * SBINS * 128, Ybuf);
    reduce_stats<<<1, 128, 0, stream>>>(statsP + 2 * SBINS * 128, statsF + 256);
    fin_kernel<<<(BATCH * 64 * NC) / 256, 256, 0, stream>>>(
        (const unsigned*)Ybuf, g2, be2, statsF + 256, out);
    (void)in_sizes; (void)n_in; (void)out_size;
}

// Round 6
// 2755.166 us; speedup vs baseline: 1.1843x; 1.0009x over previous
//
#include <hip/hip_runtime.h>
#include <math.h>

#define BATCH 8
#define NPTS 8192
#define CFEAT 64
#define NC 2048           // S centers
#define KNN 32
#define NSCOL (NC*KNN)    // 65536 columns per batch
#define R2 0.0625f        // radius^2
#define GN_EPS 1e-5f
#define SBINS 32          // stat partial bins (cuts atomic contention 32x)

// ---- workspace layout (bytes) ----
#define OFF_CIDX   0ull
#define OFF_NIDX   65536ull
#define OFF_CENT   2162688ull
#define OFF_STATSP 2359296ull            // 3 layers x 32 bins x 128 fl = 49152 B
#define OFF_STATSF 2408448ull            // 3 x 128 fl = 1536 B
#define OFF_WT     2410496ull            // 16576 fl = 66304 B
#define OFF_XALL   4194304ull            // 17,825,792 B
#define OFF_Y      23068672ull           // 134,217,728 B
#define WS_NEEDED  (OFF_Y + 8ull*64*NSCOL*4ull)   // 150 MiB

static __device__ __forceinline__ unsigned f2bf(float f) {
    unsigned u = __float_as_uint(f);
    return (u + 0x7fffu + ((u >> 16) & 1u)) >> 16;   // RNE, finite inputs
}

// ---- fused u64-key DPP max step: all-VALU, no readlane, no SALU ----
// partner = dpp(hi,lo); if (partner > mine) take partner.
// bound_ctrl=false + old=self: invalid-src lanes compare self>self -> keep.
template<int CTRL>
static __device__ __forceinline__ void dppmax64(unsigned& hi, unsigned& lo) {
    unsigned phi = (unsigned)__builtin_amdgcn_update_dpp((int)hi, (int)hi,
                                                         CTRL, 0xf, 0xf, false);
    unsigned plo = (unsigned)__builtin_amdgcn_update_dpp((int)lo, (int)lo,
                                                         CTRL, 0xf, 0xf, false);
    unsigned long long mine   = ((unsigned long long)hi  << 32) | lo;
    unsigned long long theirs = ((unsigned long long)phi << 32) | plo;
    if (theirs > mine) { hi = phi; lo = plo; }
}

// =====================================================================
// prep: zero stat partials/finals; transpose weights to [i][o] layout.
// =====================================================================
__global__ void prep_kernel(const float* __restrict__ w0, const float* __restrict__ w1,
                            const float* __restrict__ w2, float* __restrict__ statsP,
                            float* __restrict__ statsF, float* __restrict__ wt)
{
    const int t = blockIdx.x * 256 + threadIdx.x;
    if (t < 3 * SBINS * 128) statsP[t] = 0.f;
    if (t < 384) statsF[t] = 0.f;
    if (t < 64 * 67) { int o = t / 67, i = t - o * 67; wt[i * 64 + o] = w0[t]; }
    if (t < 64 * 64) { int o = t >> 6, i = t & 63;     wt[4288 + i * 64 + o] = w1[t]; }
    if (t < 128 * 64){ int o = t >> 6, i = t & 63;     wt[8384 + i * 128 + o] = w2[t]; }
}

// =====================================================================
__global__ void reduce_stats(const float* __restrict__ statsPL, float* __restrict__ statsFL)
{
    const int t = threadIdx.x;
    if (t < 128) {
        float s = 0.f;
#pragma unroll
        for (int bin = 0; bin < SBINS; ++bin) s += statsPL[bin * 128 + t];
        statsFL[t] = s;
    }
}

// =====================================================================
// build point-major input records: xall[b][p][0..2]=coords, [3..66]=feats,
// [67]=pad (272 B record, float4-aligned)
// =====================================================================
__global__ __launch_bounds__(256) void build_xall(const float* __restrict__ coords,
                                                  const float* __restrict__ feats,
                                                  float* __restrict__ xall)
{
    const int tid = blockIdx.x * 256 + threadIdx.x;   // b*NPTS + p
    const int b = tid >> 13, p = tid & (NPTS - 1);
    const float* cb = coords + (size_t)b * 3 * NPTS;
    const float* fb = feats + (size_t)b * CFEAT * NPTS;
    float* xp = xall + (size_t)tid * 68;
    xp[0] = cb[p]; xp[1] = cb[NPTS + p]; xp[2] = cb[2 * NPTS + p];
#pragma unroll
    for (int c = 0; c < CFEAT; ++c) xp[3 + c] = fb[c * NPTS + p];
    xp[67] = 0.f;
}

// =====================================================================
// FPS v8: 512 threads, 16 pts/thread; ONE change vs v7: the X/Y/Z VGPR
// pins moved INSIDE the iteration loop.
// DIAGNOSIS from R5: VGPR_Count=48 < the 64 floats of private state ->
// arrays were never register-resident; the compiler folds loop uses of
// X[j] back into ds_reads of sx/sy/sz (it proves X[j]==sx[p]; an
// init-time pin doesn't stop downstream rematerialization). Measured
// cost: VALU issue ~1816 cy/iter vs ~830 clean (VALUBusy=82% of the
// 8-CU ceiling).
// FIX: a "+v" asm pin at the TOP of every iteration is a read-write def
// the compiler can't see through -- below it, values MUST stay in
// VGPRs; LDS rematerialization is illegal. Costs 0 instructions.
// 48 pinned + 16 mind + scratch ~ 90 VGPRs < 256/wave budget
// (2 waves/SIMD). Reduce/combine/broadcast unchanged (R5-verified).
// =====================================================================
__global__ __launch_bounds__(512, 1) void fps_kernel(const float* __restrict__ coords,
                                                     int* __restrict__ cidx)
{
    extern __shared__ float smem[];
    float* sx = smem;
    float* sy = smem + NPTS;
    float* sz = smem + 2 * NPTS;
    unsigned long long* wpack = (unsigned long long*)(smem + 3 * NPTS);  // [2][8]

    const int b = blockIdx.x;
    const int t = threadIdx.x;
    const float* cb = coords + (size_t)b * 3 * NPTS;

    float X[16], Y[16], Z[16], mind[16];
#pragma unroll
    for (int j = 0; j < 16; ++j) {
        int p = t + j * 512;
        X[j] = cb[p];
        Y[j] = cb[NPTS + p];
        Z[j] = cb[2 * NPTS + p];
        sx[p] = X[j]; sy[p] = Y[j]; sz[p] = Z[j];
        mind[j] = 1e10f;
    }
    if (t == 0) cidx[b * NC] = 0;
    __syncthreads();

    int cur = 0;
    for (int it = 1; it < NC; ++it) {
        // Pin the coordinate arrays in VGPRs EVERY iteration: "+v" is a
        // read-write def -- below this point the compiler cannot fold
        // X/Y/Z uses back into LDS reads of sx/sy/sz.
#pragma unroll
        for (int j = 0; j < 16; ++j)
            asm volatile("" : "+v"(X[j]), "+v"(Y[j]), "+v"(Z[j]));

        const float lx = sx[cur], ly = sy[cur], lz = sz[cur];  // broadcast
        float bv = -1.0f; int bi = 0;
#pragma unroll
        for (int j = 0; j < 16; ++j) {
            float dx = __fsub_rn(X[j], lx);
            float dy = __fsub_rn(Y[j], ly);
            float dz = __fsub_rn(Z[j], lz);
            float d  = __fadd_rn(__fadd_rn(__fmul_rn(dx, dx), __fmul_rn(dy, dy)),
                                 __fmul_rn(dz, dz));
            float nm = fminf(mind[j], d);
            mind[j] = nm;
            if (nm > bv) { bv = nm; bi = t + j * 512; }   // strict >: lowest idx
        }
        // ---- intra-wave reduce: 6-step all-VALU DPP butterfly on u64 key ----
        unsigned hi = __float_as_uint(bv);                 // bv >= 0: uint order == float order
        unsigned lo = (unsigned)(NPTS - 1 - bi);           // larger lo == smaller index
        dppmax64<0x111>(hi, lo);   // row_shr:1
        dppmax64<0x112>(hi, lo);   // row_shr:2
        dppmax64<0x114>(hi, lo);   // row_shr:4
        dppmax64<0x118>(hi, lo);   // row_shr:8
        dppmax64<0x142>(hi, lo);   // row_bcast:15
        dppmax64<0x143>(hi, lo);   // row_bcast:31 -> lane63 has wave max
        unsigned long long pack = ((unsigned long long)hi << 32)
                                | (unsigned long long)lo;

        unsigned long long* wp = wpack + (it & 1) * 8;     // double buffer
        if ((t & 63) == 63) wp[t >> 6] = pack;             // winner is in lane 63
        __syncthreads();
        unsigned long long best = wp[0];
#pragma unroll
        for (int w = 1; w < 8; ++w) {
            unsigned long long v = wp[w];
            if (v > best) best = v;
        }
        cur = NPTS - 1 - (int)(best & 0xffffffffu);
        if (t == 0) cidx[b * NC + it] = cur;
    }
}

// =====================================================================
// Ball query -> nidx + centers. EXPANDED d2 form (cn+pn)-2*cp, no fma.
// =====================================================================
__global__ __launch_bounds__(256) void bq_kernel(const float* __restrict__ coords,
                                                 const int* __restrict__ cidx,
                                                 int* __restrict__ nidx,
                                                 float* __restrict__ centers)
{
    const int s = blockIdx.x, b = blockIdx.y, t = threadIdx.x;
    __shared__ int s_idx[KNN];
    __shared__ int s_pref[9];
    __shared__ float s_c[3];
    __shared__ float s_cn;
    const float* cb = coords + (size_t)b * 3 * NPTS;
    if (t == 0) {
        int ci = cidx[b * NC + s];
        float cx = cb[ci], cy = cb[NPTS + ci], cz = cb[2 * NPTS + ci];
        s_c[0] = cx; s_c[1] = cy; s_c[2] = cz;
        s_cn = __fadd_rn(__fadd_rn(__fmul_rn(cx, cx), __fmul_rn(cy, cy)),
                         __fmul_rn(cz, cz));
    }
    __syncthreads();
    const float cx = s_c[0], cy = s_c[1], cz = s_c[2], cn = s_cn;
    const int base = t * 32;
    int cnt = 0;
    for (int j = 0; j < 32; ++j) {
        int p = base + j;
        float x = cb[p], y = cb[NPTS + p], z = cb[2 * NPTS + p];
        float pn = __fadd_rn(__fadd_rn(__fmul_rn(x, x), __fmul_rn(y, y)), __fmul_rn(z, z));
        float cp = __fadd_rn(__fadd_rn(__fmul_rn(cx, x), __fmul_rn(cy, y)), __fmul_rn(cz, z));
        float d2 = __fsub_rn(__fadd_rn(cn, pn), __fmul_rn(2.0f, cp));
        if (d2 < R2) ++cnt;
    }
    const int lane = t & 63, wid = t >> 6;
    int incl = cnt;
    for (int o = 1; o < 64; o <<= 1) {
        int v = __shfl_up(incl, o);
        if (lane >= o) incl += v;
    }
    if (lane == 63) s_pref[wid] = incl;
    __syncthreads();
    int ex = incl - cnt;
    for (int w = 0; w < wid; ++w) ex += s_pref[w];
    if (t == 255) s_pref[8] = ex + cnt;
    if (ex < KNN && cnt > 0) {
        int slot = ex;
        for (int j = 0; j < 32 && slot < KNN; ++j) {
            int p = base + j;
            float x = cb[p], y = cb[NPTS + p], z = cb[2 * NPTS + p];
            float pn = __fadd_rn(__fadd_rn(__fmul_rn(x, x), __fmul_rn(y, y)), __fmul_rn(z, z));
            float cp = __fadd_rn(__fadd_rn(__fmul_rn(cx, x), __fmul_rn(cy, y)), __fmul_rn(cz, z));
            float d2 = __fsub_rn(__fadd_rn(cn, pn), __fmul_rn(2.0f, cp));
            if (d2 < R2) { s_idx[slot] = p; ++slot; }
        }
    }
    __syncthreads();
    const int total = s_pref[8];
    if (t < KNN) {
        int v = (total == 0) ? 0 : ((t < total) ? s_idx[t] : s_idx[0]);
        nidx[(b * NC + s) * KNN + t] = v;
    }
    if (t < 3) centers[(b * NC + s) * 3 + t] = s_c[t];
}

// =====================================================================
// Layer 1: block = 64 cols x 4 out-chunks of 16. Gather staged in LDS
// xs[68][64] fp32; per-thread state is only acc[16] (no spill).
// =====================================================================
__global__ __launch_bounds__(256) void l1_kernel(const float* __restrict__ xall,
                                                 const int* __restrict__ nidx,
                                                 const float* __restrict__ centers,
                                                 const float* __restrict__ wt,
                                                 const float* __restrict__ b0,
                                                 float* __restrict__ Y,
                                                 float* __restrict__ statsPL)
{
    __shared__ float sw[67 * 64 + 64];
    __shared__ float xs[68 * 64];
    __shared__ float s_sum[8], s_sq[8];
    const int b = blockIdx.y, t = threadIdx.x;
    const int col = t & 63, q = t >> 6;
    const int n = blockIdx.x * 64 + col;
    for (int i = t; i < 67 * 64; i += 256) sw[i] = wt[i];
    if (t < 64) sw[67 * 64 + t] = b0[t];
    if (t < 8) { s_sum[t] = 0.f; s_sq[t] = 0.f; }
    const int s = n >> 5, k = n & 31;
    const int p = nidx[(b * NC + s) * KNN + k];
    const float4* xp4 = (const float4*)(xall + (size_t)(b * NPTS + p) * 68);
    const float* cc = centers + (size_t)(b * NC + s) * 3;
#pragma unroll
    for (int r = 0; r < 4; ++r) {
        float4 v = xp4[q * 4 + r];
        int ch = (q * 4 + r) * 4;
        if (ch == 0) { v.x -= cc[0]; v.y -= cc[1]; v.z -= cc[2]; }
        xs[(ch + 0) * 64 + col] = v.x;
        xs[(ch + 1) * 64 + col] = v.y;
        xs[(ch + 2) * 64 + col] = v.z;
        xs[(ch + 3) * 64 + col] = v.w;
    }
    if (q == 3) {
        float4 v = xp4[16];
        xs[64 * 64 + col] = v.x;
        xs[65 * 64 + col] = v.y;
        xs[66 * 64 + col] = v.z;
        xs[67 * 64 + col] = v.w;
    }
    __syncthreads();
    float acc[16];
#pragma unroll
    for (int o = 0; o < 16; ++o) acc[o] = sw[67 * 64 + q * 16 + o];
    for (int i = 0; i < 67; ++i) {
        float xv = xs[i * 64 + col];
        const float* wr = sw + i * 64 + q * 16;
#pragma unroll
        for (int o = 0; o < 16; ++o) acc[o] = fmaf(wr[o], xv, acc[o]);
    }
    float* yb = Y + (size_t)b * 64 * NSCOL + n;
#pragma unroll
    for (int o = 0; o < 16; ++o) yb[(size_t)(q * 16 + o) * NSCOL] = acc[o];
#pragma unroll
    for (int g = 0; g < 2; ++g) {
        float sv = 0.f, sq = 0.f;
#pragma unroll
        for (int j = 0; j < 8; ++j) { float vv = acc[g * 8 + j]; sv += vv; sq = fmaf(vv, vv, sq); }
#pragma unroll
        for (int o = 32; o > 0; o >>= 1) { sv += __shfl_xor(sv, o); sq += __shfl_xor(sq, o); }
        if ((t & 63) == 0) { atomicAdd(&s_sum[q * 2 + g], sv); atomicAdd(&s_sq[q * 2 + g], sq); }
    }
    __syncthreads();
    if (t < 16) {
        const int bin = blockIdx.x & (SBINS - 1);
        const int g = t >> 1, kk = t & 1;
        atomicAdd(&statsPL[bin * 128 + (b * 8 + g) * 2 + kk], kk ? s_sq[g] : s_sum[g]);
    }
}

// =====================================================================
// Layer 2: in-place, block = 64 cols x 4 out-chunks of 16.
// =====================================================================
__global__ __launch_bounds__(256) void l2_kernel(const float* __restrict__ wt1,
                                                 const float* __restrict__ b1,
                                                 const float* __restrict__ g0,
                                                 const float* __restrict__ be0,
                                                 const float* __restrict__ statsF_in,
                                                 float* __restrict__ statsPL,
                                                 float* __restrict__ Y)
{
    __shared__ float sw[64 * 64 + 64];
    __shared__ float xs[64 * 64];
    __shared__ float sA[64], sB[64];
    __shared__ float s_sum[8], s_sq[8];
    const int b = blockIdx.y, t = threadIdx.x;
    const int col = t & 63, q = t >> 6;
    const int n = blockIdx.x * 64 + col;
    for (int i = t; i < 64 * 64; i += 256) sw[i] = wt1[i];
    if (t < 64) {
        sw[64 * 64 + t] = b1[t];
        const int g = t >> 3;
        const float inv = 1.0f / (8.0f * NSCOL);
        float mu = statsF_in[(b * 8 + g) * 2 + 0] * inv;
        float var = statsF_in[(b * 8 + g) * 2 + 1] * inv - mu * mu;
        float A = (1.0f / sqrtf(var + GN_EPS)) * g0[t];
        sA[t] = A; sB[t] = be0[t] - mu * A;
    }
    if (t < 8) { s_sum[t] = 0.f; s_sq[t] = 0.f; }
    __syncthreads();
    float* yb = Y + (size_t)b * 64 * NSCOL + n;
#pragma unroll
    for (int r = 0; r < 16; ++r) {
        int i = q * 16 + r;
        float raw = yb[(size_t)i * NSCOL];
        float v = fmaf(raw, sA[i], sB[i]);
        xs[i * 64 + col] = v * __builtin_amdgcn_rcpf(1.0f + __expf(-v));
    }
    __syncthreads();
    float acc[16];
#pragma unroll
    for (int o = 0; o < 16; ++o) acc[o] = sw[64 * 64 + q * 16 + o];
    for (int i = 0; i < 64; ++i) {
        float xv = xs[i * 64 + col];
        const float* wr = sw + i * 64 + q * 16;
#pragma unroll
        for (int o = 0; o < 16; ++o) acc[o] = fmaf(wr[o], xv, acc[o]);
    }
#pragma unroll
    for (int o = 0; o < 16; ++o) yb[(size_t)(q * 16 + o) * NSCOL] = acc[o];
#pragma unroll
    for (int g = 0; g < 2; ++g) {
        float sv = 0.f, sq = 0.f;
#pragma unroll
        for (int j = 0; j < 8; ++j) { float vv = acc[g * 8 + j]; sv += vv; sq = fmaf(vv, vv, sq); }
#pragma unroll
        for (int o = 32; o > 0; o >>= 1) { sv += __shfl_xor(sv, o); sq += __shfl_xor(sq, o); }
        if ((t & 63) == 0) { atomicAdd(&s_sum[q * 2 + g], sv); atomicAdd(&s_sq[q * 2 + g], sq); }
    }
    __syncthreads();
    if (t < 16) {
        const int bin = blockIdx.x & (SBINS - 1);
        const int g = t >> 1, kk = t & 1;
        atomicAdd(&statsPL[bin * 128 + (b * 8 + g) * 2 + kk], kk ? s_sq[g] : s_sum[g]);
    }
}

// =====================================================================
// Layer 3: in-place, block = 64 cols x 4 out-chunks of 32 (128 out).
// Output bf16 pair-packed into the same 256B/col footprint.
// =====================================================================
__global__ __launch_bounds__(256) void l3_kernel(const float* __restrict__ wt2,
                                                 const float* __restrict__ b2,
                                                 const float* __restrict__ g1,
                                                 const float* __restrict__ be1,
                                                 const float* __restrict__ statsF_in,
                                                 float* __restrict__ statsPL,
                                                 float* __restrict__ Y)
{
    __shared__ float sw[64 * 128 + 128];
    __shared__ float xs[64 * 64];
    __shared__ float sA[64], sB[64];
    __shared__ float s_sum[8], s_sq[8];
    const int b = blockIdx.y, t = threadIdx.x;
    const int col = t & 63, q = t >> 6;
    const int n = blockIdx.x * 64 + col;
    for (int i = t; i < 64 * 128; i += 256) sw[i] = wt2[i];
    if (t < 128) sw[64 * 128 + t] = b2[t];
    if (t < 64) {
        const int g = t >> 3;
        const float inv = 1.0f / (8.0f * NSCOL);
        float mu = statsF_in[(b * 8 + g) * 2 + 0] * inv;
        float var = statsF_in[(b * 8 + g) * 2 + 1] * inv - mu * mu;
        float A = (1.0f / sqrtf(var + GN_EPS)) * g1[t];
        sA[t] = A; sB[t] = be1[t] - mu * A;
    }
    if (t < 8) { s_sum[t] = 0.f; s_sq[t] = 0.f; }
    __syncthreads();
    float* yb = Y + (size_t)b * 64 * NSCOL + n;
#pragma unroll
    for (int r = 0; r < 16; ++r) {
        int i = q * 16 + r;
        float raw = yb[(size_t)i * NSCOL];
        float v = fmaf(raw, sA[i], sB[i]);
        xs[i * 64 + col] = v * __builtin_amdgcn_rcpf(1.0f + __expf(-v));
    }
    __syncthreads();
    float acc[32];
#pragma unroll
    for (int o = 0; o < 32; ++o) acc[o] = sw[64 * 128 + q * 32 + o];
    for (int i = 0; i < 64; ++i) {
        float xv = xs[i * 64 + col];
        const float* wr = sw + i * 128 + q * 32;
#pragma unroll
        for (int o = 0; o < 32; ++o) acc[o] = fmaf(wr[o], xv, acc[o]);
    }
#pragma unroll
    for (int g = 0; g < 2; ++g) {
        float sv = 0.f, sq = 0.f;
#pragma unroll
        for (int j = 0; j < 16; ++j) { float vv = acc[g * 16 + j]; sv += vv; sq = fmaf(vv, vv, sq); }
#pragma unroll
        for (int o = 32; o > 0; o >>= 1) { sv += __shfl_xor(sv, o); sq += __shfl_xor(sq, o); }
        if ((t & 63) == 0) { atomicAdd(&s_sum[q * 2 + g], sv); atomicAdd(&s_sq[q * 2 + g], sq); }
    }
    unsigned* yu = (unsigned*)yb;
#pragma unroll
    for (int j = 0; j < 16; ++j) {
        unsigned u = f2bf(acc[2 * j]) | (f2bf(acc[2 * j + 1]) << 16);
        yu[(size_t)(q * 16 + j) * NSCOL] = u;
    }
    __syncthreads();
    if (t < 16) {
        const int bin = blockIdx.x & (SBINS - 1);
        const int g = t >> 1, kk = t & 1;
        atomicAdd(&statsPL[bin * 128 + (b * 8 + g) * 2 + kk], kk ? s_sq[g] : s_sum[g]);
    }
}

// =====================================================================
// Finalize: GN3 + SiLU + max over K. Thread per (b, channel-PAIR, s).
// =====================================================================
__global__ __launch_bounds__(256) void fin_kernel(const unsigned* __restrict__ Yu,
                                                  const float* __restrict__ g2,
                                                  const float* __restrict__ be2,
                                                  const float* __restrict__ stats,
                                                  float* __restrict__ out)
{
    const int tid = blockIdx.x * 256 + threadIdx.x;
    const int s = tid & (NC - 1);
    const int cp = (tid >> 11) & 63;
    const int b = tid >> 17;
    const int g = cp >> 3;
    const float inv = 1.0f / (16.0f * NSCOL);
    float mu = stats[(b * 8 + g) * 2 + 0] * inv;
    float var = stats[(b * 8 + g) * 2 + 1] * inv - mu * mu;
    float rs = 1.0f / sqrtf(var + GN_EPS);
    const int c0 = cp * 2, c1 = c0 + 1;
    float A0 = rs * g2[c0], B0 = be2[c0] - mu * A0;
    float A1 = rs * g2[c1], B1 = be2[c1] - mu * A1;
    const unsigned* yb = Yu + (size_t)(b * 64 + cp) * NSCOL + s * KNN;
    float m0 = -INFINITY, m1 = -INFINITY;
#pragma unroll
    for (int qq = 0; qq < 8; ++qq) {
        uint4 v = ((const uint4*)yb)[qq];
        unsigned uu[4] = {v.x, v.y, v.z, v.w};
#pragma unroll
        for (int r = 0; r < 4; ++r) {
            float f0 = __uint_as_float(uu[r] << 16);
            float f1 = __uint_as_float(uu[r] & 0xffff0000u);
            float v0 = fmaf(f0, A0, B0);
            v0 = v0 * __builtin_amdgcn_rcpf(1.0f + __expf(-v0));
            m0 = fmaxf(m0, v0);
            float v1 = fmaf(f1, A1, B1);
            v1 = v1 * __builtin_amdgcn_rcpf(1.0f + __expf(-v1));
            m1 = fmaxf(m1, v1);
        }
    }
    out[(size_t)(b * 128 + c0) * NC + s] = m0;
    out[(size_t)(b * 128 + c1) * NC + s] = m1;
}

// =====================================================================
extern "C" void kernel_launch(void* const* d_in, const int* in_sizes, int n_in,
                              void* d_out, int out_size, void* d_ws, size_t ws_size,
                              hipStream_t stream)
{
    if (ws_size < WS_NEEDED) return;

    const float* coords = (const float*)d_in[0];
    const float* feats  = (const float*)d_in[1];
    const float* w0  = (const float*)d_in[2];
    const float* b0  = (const float*)d_in[3];
    const float* g0  = (const float*)d_in[4];
    const float* be0 = (const float*)d_in[5];
    const float* w1  = (const float*)d_in[6];
    const float* b1  = (const float*)d_in[7];
    const float* g1  = (const float*)d_in[8];
    const float* be1 = (const float*)d_in[9];
    const float* w2  = (const float*)d_in[10];
    const float* b2  = (const float*)d_in[11];
    const float* g2  = (const float*)d_in[12];
    const float* be2 = (const float*)d_in[13];
    float* out = (float*)d_out;

    char* ws = (char*)d_ws;
    int*   cidx    = (int*)(ws + OFF_CIDX);
    int*   nidx    = (int*)(ws + OFF_NIDX);
    float* centers = (float*)(ws + OFF_CENT);
    float* statsP  = (float*)(ws + OFF_STATSP);   // [3][SBINS][128]
    float* statsF  = (float*)(ws + OFF_STATSF);   // [3][128]
    float* wt      = (float*)(ws + OFF_WT);
    float* xall    = (float*)(ws + OFF_XALL);
    float* Ybuf    = (float*)(ws + OFF_Y);

    prep_kernel<<<48, 256, 0, stream>>>(w0, w1, w2, statsP, statsF, wt);
    build_xall<<<(BATCH * NPTS) / 256, 256, 0, stream>>>(coords, feats, xall);
    // dynamic LDS: 3*NPTS floats (coords) + 16 u64 packs (2x8 dbuf)
    fps_kernel<<<BATCH, 512, 3 * NPTS * 4 + 128, stream>>>(coords, cidx);
    bq_kernel<<<dim3(NC, BATCH), 256, 0, stream>>>(coords, cidx, nidx, centers);

    const dim3 lgrid(NSCOL / 64, BATCH);
    l1_kernel<<<lgrid, 256, 0, stream>>>(xall, nidx, centers, wt, b0, Ybuf, statsP);
    reduce_stats<<<1, 128, 0, stream>>>(statsP, statsF);
    l2_kernel<<<lgrid, 256, 0, stream>>>(wt + 4288, b1, g0, be0,
                                         statsF, statsP + SBINS * 128, Ybuf);
    reduce_stats<<<1, 128, 0, stream>>>(statsP + SBINS * 128, statsF + 128);
    l3_kernel<<<lgrid, 256, 0, stream>>>(wt + 8384, b2, g1, be1,
                                         statsF + 128, statsP + 2 * SBINS * 128, Ybuf);
    reduce_stats<<<1, 128, 0, stream>>>(statsP + 2 * SBINS * 128, statsF + 256);
    fin_kernel<<<(BATCH * 64 * NC) / 256, 256, 0, stream>>>(
        (const unsigned*)Ybuf, g2, be2, statsF + 256, out);
    (void)in_sizes; (void)n_in; (void)out_size;
}